// Round 7
// baseline (2426.322 us; speedup 1.0000x reference)
//
#include <hip/hip_runtime.h>

// ---------------------------------------------------------------------------
// EfficientDet head on MFMA (gfx950), split-bf16 (hi+lo) fp32-accurate GEMM.
// All convs = implicit GEMM: C[co][n] = W[co][k] * Im2col[k][n].
// Activations: NHWC bf16 hi/lo planes; 3x3 inputs spatially zero-padded P=S+2.
// K order for 3x3: k = (r*3+s)*256 + ci  (tap-major -> contiguous ci chunks).
// 3 MFMAs per tile-pair: AhiBhi + AhiBlo + AloBhi  (error ~2^-17 relative).
//
// R7: conv3g chunk = 8-phase 2D snake over (i-pair, j-pair) quadrants:
//   (0,0)(1,0)(2,0)(3,0)(3,1)(2,1)(1,1)(0,1). Each phase: LGK(0) for the
//   prefetch issued last phase -> prefetch next phase's 4-read batch into a
//   dead slot -> 12 MFMAs (96/CU ~ 465cyc covers 32 reads/CU ~ 384cyc).
//   Head exposure = 8 reads (A01+B01) vs R6's 20. A = two rolling 2-pair
//   slots X/Y (64 frag VGPR total vs 96); snake turn reuses A67 free; cost
//   +8 re-reads/wave/chunk (256KB/CU ~ 3080cyc < 3725cyc MFMA floor).
//   Double-buffered 2x64KB LDS, per-chunk vmcnt(0)+barrier (triple buffer
//   would need 192KB > 160KB LDS). Numerics bit-identical per acc cell.
// 1x1 lateral + head-scatter convs keep the R1 128^2 global_load_lds kernel.
// ---------------------------------------------------------------------------

typedef unsigned short ush;
typedef __attribute__((ext_vector_type(8))) short v8s;
typedef __attribute__((ext_vector_type(4))) float v4f;

constexpr int TOTAL_ANCH = 196416;  // 9 * (128^2+64^2+32^2+16^2+8^2)

#define VMW(n) asm volatile("s_waitcnt vmcnt(" #n ")" ::: "memory")
#define LGK(n) asm volatile("s_waitcnt lgkmcnt(" #n ")" ::: "memory")
#define SB0()  __builtin_amdgcn_sched_barrier(0)

__device__ __forceinline__ ush f2bf(float x) {
    unsigned u = __builtin_bit_cast(unsigned, x);
    u += 0x7FFFu + ((u >> 16) & 1u);
    return (ush)(u >> 16);
}
__device__ __forceinline__ float bf2f(ush h) {
    unsigned u = ((unsigned)h) << 16;
    return __builtin_bit_cast(float, u);
}
__device__ __forceinline__ void splitf(float x, ush& hi, ush& lo) {
    hi = f2bf(x);
    lo = f2bf(x - bf2f(hi));
}

__device__ __forceinline__ void gl_lds16(const ush* g, short* l) {
    __builtin_amdgcn_global_load_lds(
        (const __attribute__((address_space(1))) unsigned*)(const void*)g,
        (__attribute__((address_space(3))) unsigned*)l, 16, 0, 0);
}

// per-level work descriptors (kernel args by value)
struct Lvl3 {
    const ush* xh; const ush* xl;    // input planes (padded NHWC hi/lo)
    ush* yh; ush* yl;                // output planes
    const float* bias;
    int wofs, logS, logHW, bstart;   // weight elem offset; block range start
};
struct Tab3 { Lvl3 l[4]; };

struct LvlS {
    const ush* xh; const ush* xl;    // input planes (unpadded NHWC hi/lo)
    int abase, logHW, bstart, ibase;
};
struct TabS { LvlS l[4]; };

// ---------------------------------------------------------------------------
// conv3g: deep 3x3 conv, fused multi-level. K=2304, Cout=256, 256 px/block.
// 8 waves: wm=w&1 (co half, 128 rows), wn=w>>1 (px quarter, 64 cols).
// LDS buffer (64KB): Ah[256][32] | Al | Bh[256][32] | Bl (8192 shorts each).
// Staging: role=w>>1 (0:Ah 1:Al 2:Bh 3:Bl), part=w&1 (128-row half); every
// wave 8 x gl_lds16 per chunk. Slot swizzle (both sides, proven 0-conflict):
// seg(row,slot) = slot ^ ((row>>1)&3).
// OM: 0 = padded NHWC hi/lo out; 1 = unpadded NHWC hi/lo out.  BNR: BN+ReLU.
// ---------------------------------------------------------------------------
#define MFMA3(AH, AL, BH, BL, ACC)                                            \
    ACC = __builtin_amdgcn_mfma_f32_16x16x32_bf16(AH, BH, ACC, 0, 0, 0);      \
    ACC = __builtin_amdgcn_mfma_f32_16x16x32_bf16(AH, BL, ACC, 0, 0, 0);      \
    ACC = __builtin_amdgcn_mfma_f32_16x16x32_bf16(AL, BH, ACC, 0, 0, 0);

// load A i-pair IP (rows 2IP*16..) into slot S  (4 x ds_read_b128)
#define PFA(S, IP, BP)                                                        \
    S##h0 = *(const v8s*)((BP) + abA + (2*(IP)) * 512);                       \
    S##h1 = *(const v8s*)((BP) + abA + (2*(IP)+1) * 512);                     \
    S##l0 = *(const v8s*)((BP) + abA + 8192 + (2*(IP)) * 512);                \
    S##l1 = *(const v8s*)((BP) + abA + 8192 + (2*(IP)+1) * 512);

// load B j-pair JP into slot S  (4 x ds_read_b128)
#define PFB(S, JP, BP)                                                        \
    S##h0 = *(const v8s*)((BP) + abB + (2*(JP)) * 512);                       \
    S##h1 = *(const v8s*)((BP) + abB + (2*(JP)+1) * 512);                     \
    S##l0 = *(const v8s*)((BP) + abB + 8192 + (2*(JP)) * 512);                \
    S##l1 = *(const v8s*)((BP) + abB + 8192 + (2*(JP)+1) * 512);

// 12 MFMAs: A slot SA (i-pair IP), B slot SB (j-pair JP)
#define MF12(SA, SB, IP, JP)                                                  \
    __builtin_amdgcn_s_setprio(1);                                            \
    MFMA3(SA##h0, SA##l0, SB##h0, SB##l0, acc[2*(IP)  ][2*(JP)  ]);           \
    MFMA3(SA##h1, SA##l1, SB##h0, SB##l0, acc[2*(IP)+1][2*(JP)  ]);           \
    MFMA3(SA##h0, SA##l0, SB##h1, SB##l1, acc[2*(IP)  ][2*(JP)+1]);           \
    MFMA3(SA##h1, SA##l1, SB##h1, SB##l1, acc[2*(IP)+1][2*(JP)+1]);           \
    __builtin_amdgcn_s_setprio(0);

template <int OM, bool BNR>
__global__ __launch_bounds__(512, 2)
void conv3g(Tab3 T,
            const ush* __restrict__ Wh, const ush* __restrict__ Wl,
            const float* __restrict__ bng, const float* __restrict__ bnb,
            const float* __restrict__ bnm, const float* __restrict__ bnv)
{
    constexpr int K = 2304, KC = 72;
    constexpr int BUFS = 32768;   // shorts per buffer (64KB)

    // bijective XCD-aware swizzle on the 1-D grid
    const int nwg = gridDim.x;
    const int flat = blockIdx.x;
    const int xcd = flat & 7, sidx = flat >> 3;
    const int q = nwg >> 3, r8 = nwg & 7;
    const int nf = (xcd < r8 ? xcd * (q + 1) : r8 * (q + 1) + (xcd - r8) * q) + sidx;

    // level lookup
    int li = 0;
    if (nf >= T.l[1].bstart) li = 1;
    if (nf >= T.l[2].bstart) li = 2;
    if (nf >= T.l[3].bstart) li = 3;
    const int logS = T.l[li].logS, logHW = T.l[li].logHW;
    const int S = 1 << logS, HW = 1 << logHW, P = S + 2;
    const ush* __restrict__ Xh = T.l[li].xh;
    const ush* __restrict__ Xl = T.l[li].xl;
    ush* __restrict__ Yh = T.l[li].yh;
    ush* __restrict__ Yl = T.l[li].yl;
    const float* __restrict__ bias = T.l[li].bias;
    const int wofs = T.l[li].wofs;
    const int n0 = (nf - T.l[li].bstart) * 256;

    __shared__ __align__(16) short lds[2][BUFS];
    // buffer layout (shorts): Ah 0 | Al 8192 | Bh 16384 | Bl 24576

    const int tid = threadIdx.x;
    const int lane = tid & 63, w = tid >> 6;
    const int wm = w & 1, wn = w >> 1;       // wave tile: 128 co x 64 px
    const int l15 = lane & 15, l4 = lane >> 4;
    const int lr = lane >> 2, ls = lane & 3;
    const int sw = ls ^ ((lr >> 1) & 3);

    const int role = w >> 1, part = w & 1;   // 0:Ah 1:Al 2:Bh 3:Bl
    const ush* gsrc = role == 0 ? Wh + wofs : role == 1 ? Wl + wofs
                    : role == 2 ? Xh : Xl;
    const int poff = role * 8192 + part * 4096;

    int sb[8];
    if (role < 2) {
#pragma unroll
        for (int t = 0; t < 8; ++t)
            sb[t] = (part * 128 + t * 16 + lr) * K + sw * 8;
    } else {
#pragma unroll
        for (int t = 0; t < 8; ++t) {
            const int p = n0 + part * 128 + t * 16 + lr;
            const int bb = p >> logHW, hw = p & (HW - 1);
            const int oh = hw >> logS, ow = hw & (S - 1);
            sb[t] = ((bb * P + oh + 1) * P + ow + 1) * 256 + sw * 8;
        }
    }

    // stage full chunk c into buffer u (8 x 16B DMA per wave, uniform)
    auto stage = [&](int u, int c) {
        short* db = &lds[0][0] + u * BUFS + poff;
        int coff;
        if (role < 2) coff = c * 32;
        else {
            const int rs = c >> 3;             // tap 0..8 (uniform)
            const int rr = (rs * 11) >> 5;     // rs / 3
            const int ss = rs - 3 * rr;
            coff = ((rr - 1) * P + (ss - 1)) * 256 + (c & 7) * 32;
        }
#pragma unroll
        for (int t = 0; t < 8; ++t)
            gl_lds16(gsrc + (sb[t] + coff), db + t * 512);
    };

    // fragment base offsets within a buffer (shorts); per-i/j step = 512
    const int slr = (l4 ^ ((l15 >> 1) & 3)) * 8;
    const int abA = (wm * 128 + l15) * 32 + slr;
    const int abB = 16384 + (wn * 64 + l15) * 32 + slr;

    v4f acc[8][4] = {};
    // rolling fragment slots: A pairs in X/Y, B pairs in U/V (4 v8s each)
    v8s Xh0, Xh1, Xl0, Xl1;
    v8s Yh0, Yh1, Yl0, Yl1;
    v8s Uh0, Uh1, Ul0, Ul1;
    v8s Vh0, Vh1, Vl0, Vl1;

    // prologue: chunk 0 staged; wait + barrier
    stage(0, 0);
    VMW(0);
    SB0();
    __builtin_amdgcn_s_barrier();

    int cur = 0;
    for (int c = 0; c < KC; ++c) {
        const bool pf = (c + 1) < KC;
        const short* bp = &lds[0][0] + cur * BUFS;

        // head: phase-0 operands (8 ds reads), then next-chunk DMA (vmcnt)
        PFA(X, 0, bp); PFB(U, 0, bp);
        if (pf) stage(cur ^ 1, c + 1);

        // 8-phase snake: each phase waits last phase's prefetch, prefetches
        // the next phase's batch into a dead slot, runs 12 MFMAs.
        LGK(0); SB0(); PFA(Y, 1, bp); MF12(X, U, 0, 0);
        LGK(0); SB0(); PFA(X, 2, bp); MF12(Y, U, 1, 0);
        LGK(0); SB0(); PFA(Y, 3, bp); MF12(X, U, 2, 0);
        LGK(0); SB0(); PFB(V, 1, bp); MF12(Y, U, 3, 0);
        LGK(0); SB0();                MF12(Y, V, 3, 1);   // A67 reused (turn)
        LGK(0); SB0(); PFA(Y, 1, bp); MF12(X, V, 2, 1);   // A45 still in X
        LGK(0); SB0(); PFA(X, 0, bp); MF12(Y, V, 1, 1);
        LGK(0); SB0();                MF12(X, V, 0, 1);

        if (pf) VMW(0);          // drains DMA issued at top of THIS chunk
        SB0();
        __builtin_amdgcn_s_barrier();
        cur ^= 1;
    }

    // ---- epilogue: col = lane&15 (pixel), row = (lane>>4)*4+e (co) ----
#pragma unroll
    for (int i = 0; i < 8; ++i) {
        const int co = wm * 128 + i * 16 + l4 * 4;
        float sc[4], sh[4];
#pragma unroll
        for (int e = 0; e < 4; ++e) {
            if (BNR) {
                const float inv = bng[co + e] * rsqrtf(bnv[co + e] + 1e-5f);
                sc[e] = inv;
                sh[e] = (bias[co + e] - bnm[co + e]) * inv + bnb[co + e];
            } else { sc[e] = 1.f; sh[e] = bias[co + e]; }
        }
#pragma unroll
        for (int j = 0; j < 4; ++j) {
            const int ncol = n0 + wn * 64 + j * 16 + l15;
            const int b  = ncol >> logHW;
            const int hw = ncol & (HW - 1);
            float val[4];
#pragma unroll
            for (int e = 0; e < 4; ++e) {
                float x = acc[i][j][e] * sc[e] + sh[e];
                if (BNR) x = fmaxf(x, 0.f);
                val[e] = x;
            }
            int pidx;
            if (OM == 0) {
                const int oh = hw >> logS, ow = hw & (S - 1);
                pidx = (b * P + oh + 1) * P + ow + 1;
            } else {
                pidx = ncol;
            }
            const int addr = pidx * 256 + co;
            ush hs[4], ls2[4];
#pragma unroll
            for (int e = 0; e < 4; ++e) splitf(val[e], hs[e], ls2[e]);
            *(uint2*)&Yh[addr] = make_uint2(hs[0] | ((unsigned)hs[1] << 16),
                                            hs[2] | ((unsigned)hs[3] << 16));
            *(uint2*)&Yl[addr] = make_uint2(ls2[0] | ((unsigned)ls2[1] << 16),
                                            ls2[2] | ((unsigned)ls2[3] << 16));
        }
    }
}

// ---------------------------------------------------------------------------
// Fused scatter head-conv2 (1x1, K=256, Cout=9*DD, fp32 scatter epilogue).
// 4 waves, 128 px/block, co0 = 0 (Cout <= 128; weights zero-padded to 128).
// ---------------------------------------------------------------------------
template <int DD>
__global__ __launch_bounds__(256, 3)
void conv_sf(TabS T, const ush* __restrict__ Wh, const ush* __restrict__ Wl,
             const float* __restrict__ bias, float* __restrict__ out)
{
    constexpr int K = 256, KC = 8, Cout = 9 * DD;
    constexpr int coloff = (DD == 10) ? 4 : 0;

    const int nwg = gridDim.x;
    const int flat = blockIdx.x;
    const int xcd = flat & 7, sidx = flat >> 3;
    const int q = nwg >> 3, r8 = nwg & 7;
    const int nf = (xcd < r8 ? xcd * (q + 1) : r8 * (q + 1) + (xcd - r8) * q) + sidx;

    int li = 0;
    if (nf >= T.l[1].bstart) li = 1;
    if (nf >= T.l[2].bstart) li = 2;
    if (nf >= T.l[3].bstart) li = 3;
    const int logHW = T.l[li].logHW;
    const int HW = 1 << logHW;
    const ush* __restrict__ Xh = T.l[li].xh;
    const ush* __restrict__ Xl = T.l[li].xl;
    const int abase = T.l[li].abase, ibase = T.l[li].ibase;
    const int n0 = (nf - T.l[li].bstart) * 128;

    __shared__ short lds[4][128][32];

    const int tid = threadIdx.x;
    const int lane = tid & 63;
    const int w = tid >> 6;
    const int wm = w & 1, wn = w >> 1;
    const int l15 = lane & 15, l4 = lane >> 4;
    const int lr = lane >> 2, ls = lane & 3;
    const int sw = ls ^ ((lr >> 1) & 3);
    const ush* gsrc = (w == 0) ? Wh : (w == 1) ? Wl : (w == 2) ? Xh : Xl;
    int sb[8];
    if (w < 2) {
#pragma unroll
        for (int t = 0; t < 8; ++t)
            sb[t] = (t * 16 + lr) * K + sw * 8;
    } else {
#pragma unroll
        for (int t = 0; t < 8; ++t)
            sb[t] = (n0 + t * 16 + lr) * 256 + sw * 8;
    }
    short* mypl = &lds[w][0][0];
    const int slA = (l4 ^ ((l15 >> 1) & 3)) * 8;

    v4f acc[4][4] = {};

    for (int c = 0; c < KC; ++c) {
        const int coff = c * 32;
#pragma unroll
        for (int t = 0; t < 8; ++t)
            gl_lds16(gsrc + (sb[t] + coff), mypl + t * 512);

        __syncthreads();

        v8s ah[4], al[4];
#pragma unroll
        for (int i = 0; i < 4; ++i) {
            ah[i] = *(const v8s*)&lds[0][wm * 64 + i * 16 + l15][slA];
            al[i] = *(const v8s*)&lds[1][wm * 64 + i * 16 + l15][slA];
        }
#pragma unroll
        for (int j = 0; j < 4; ++j) {
            const v8s bh = *(const v8s*)&lds[2][wn * 64 + j * 16 + l15][slA];
            const v8s bl = *(const v8s*)&lds[3][wn * 64 + j * 16 + l15][slA];
#pragma unroll
            for (int i = 0; i < 4; ++i) {
                acc[i][j] = __builtin_amdgcn_mfma_f32_16x16x32_bf16(ah[i], bh, acc[i][j], 0, 0, 0);
                acc[i][j] = __builtin_amdgcn_mfma_f32_16x16x32_bf16(ah[i], bl, acc[i][j], 0, 0, 0);
                acc[i][j] = __builtin_amdgcn_mfma_f32_16x16x32_bf16(al[i], bh, acc[i][j], 0, 0, 0);
            }
        }
        __syncthreads();
    }

#pragma unroll
    for (int i = 0; i < 4; ++i) {
        const int co = wm * 64 + i * 16 + l4 * 4;
        float sh[4];
#pragma unroll
        for (int e = 0; e < 4; ++e)
            sh[e] = (co + e < Cout) ? bias[co + e] : 0.f;
#pragma unroll
        for (int j = 0; j < 4; ++j) {
            const int ncol = n0 + wn * 64 + j * 16 + l15;
            const int b  = ncol >> logHW;
            const int hw = ncol & (HW - 1);
#pragma unroll
            for (int e = 0; e < 4; ++e) {
                const int c2 = co + e;
                if (c2 < Cout) {
                    const float val = acc[i][j][e] + sh[e];
                    const int a = c2 / DD, cl = c2 - a * DD;
                    out[(size_t)((b + ibase) * TOTAL_ANCH + abase + hw * 9 + a) * 14
                        + coloff + cl] = val;
                }
            }
        }
    }
}

// ---------------------------------------------------------------------------
// R1 128^2 kernel — retained for the 1x1 lateral convs (KS=1, OM=0).
// ---------------------------------------------------------------------------
template <int KS, int OM, bool BNR, int DD>
__global__ __launch_bounds__(256, 3)
void conv_mfma(const ush* __restrict__ Xh, const ush* __restrict__ Xl,
               const ush* __restrict__ Wh, const ush* __restrict__ Wl,
               const float* __restrict__ bias,
               ush* __restrict__ Yh, ush* __restrict__ Yl,
               int K, int logS, int logHW, int Kin)
{
    const int tid = threadIdx.x;

    const int nwg  = gridDim.x * gridDim.y;
    const int flat = blockIdx.y * gridDim.x + blockIdx.x;
    const int xcd = flat & 7, sidx = flat >> 3;
    const int q = nwg >> 3, r8 = nwg & 7;
    const int nf = (xcd < r8 ? xcd * (q + 1) : r8 * (q + 1) + (xcd - r8) * q) + sidx;
    int bx, by;
    if (gridDim.y == 2) { bx = nf >> 1; by = nf & 1; }
    else                { bx = nf;      by = 0;      }

    const int n0  = bx * 128;
    const int co0 = by * 128;
    const int S = 1 << logS, HW = 1 << logHW, P = S + 2;

    __shared__ short lds[4][128][32];

    const int lane = tid & 63;
    const int w = tid >> 6;
    const int wm = w & 1, wn = w >> 1;
    const int l15 = lane & 15, l4 = lane >> 4;

    const int lr = lane >> 2, ls = lane & 3;
    const int sw = ls ^ ((lr >> 1) & 3);
    const ush* gsrc = (w == 0) ? Wh : (w == 1) ? Wl : (w == 2) ? Xh : Xl;
    int sb[8];
    if (w < 2) {
#pragma unroll
        for (int t = 0; t < 8; ++t)
            sb[t] = (co0 + t * 16 + lr) * K + sw * 8;
    } else {
#pragma unroll
        for (int t = 0; t < 8; ++t) {
            const int p = n0 + t * 16 + lr;
            sb[t] = p * Kin + sw * 8;
        }
    }
    short* mypl = &lds[w][0][0];

    const int KC = K >> 5;
    const int slA = (l4 ^ ((l15 >> 1) & 3)) * 8;

    v4f acc[4][4] = {};

    for (int c = 0; c < KC; ++c) {
        const int coff = c * 32;
#pragma unroll
        for (int t = 0; t < 8; ++t)
            gl_lds16(gsrc + (sb[t] + coff), mypl + t * 512);

        __syncthreads();

        v8s ah[4], al[4];
#pragma unroll
        for (int i = 0; i < 4; ++i) {
            ah[i] = *(const v8s*)&lds[0][wm * 64 + i * 16 + l15][slA];
            al[i] = *(const v8s*)&lds[1][wm * 64 + i * 16 + l15][slA];
        }
#pragma unroll
        for (int j = 0; j < 4; ++j) {
            const v8s bh = *(const v8s*)&lds[2][wn * 64 + j * 16 + l15][slA];
            const v8s bl = *(const v8s*)&lds[3][wn * 64 + j * 16 + l15][slA];
#pragma unroll
            for (int i = 0; i < 4; ++i) {
                acc[i][j] = __builtin_amdgcn_mfma_f32_16x16x32_bf16(ah[i], bh, acc[i][j], 0, 0, 0);
                acc[i][j] = __builtin_amdgcn_mfma_f32_16x16x32_bf16(ah[i], bl, acc[i][j], 0, 0, 0);
                acc[i][j] = __builtin_amdgcn_mfma_f32_16x16x32_bf16(al[i], bh, acc[i][j], 0, 0, 0);
            }
        }
        __syncthreads();
    }

#pragma unroll
    for (int i = 0; i < 4; ++i) {
        const int cob = wm * 64 + i * 16 + l4 * 4;
        const int co  = co0 + cob;
        float sh[4];
#pragma unroll
        for (int e = 0; e < 4; ++e) sh[e] = bias[co + e];
#pragma unroll
        for (int j = 0; j < 4; ++j) {
            const int ncol = n0 + wn * 64 + j * 16 + l15;
            const int b  = ncol >> logHW;
            const int hw = ncol & (HW - 1);
            float val[4];
#pragma unroll
            for (int e = 0; e < 4; ++e) val[e] = acc[i][j][e] + sh[e];
            int pidx;
            if (OM == 0) {
                const int oh = hw >> logS, ow = hw & (S - 1);
                pidx = (b * P + oh + 1) * P + ow + 1;
            } else {
                pidx = ncol;
            }
            const int addr = pidx * 256 + co;
            ush hs[4], ls2[4];
#pragma unroll
            for (int e = 0; e < 4; ++e) splitf(val[e], hs[e], ls2[e]);
            *(uint2*)&Yh[addr] = make_uint2(hs[0] | ((unsigned)hs[1] << 16),
                                            hs[2] | ((unsigned)hs[3] << 16));
            *(uint2*)&Yl[addr] = make_uint2(ls2[0] | ((unsigned)ls2[1] << 16),
                                            ls2[2] | ((unsigned)ls2[3] << 16));
        }
    }
}

// ---- prep / glue kernels -------------------------------------------------

__global__ void w3_prep(const float* __restrict__ W, ush* __restrict__ wh,
                        ush* __restrict__ wl, int total) {
    const int idx = blockIdx.x * 256 + threadIdx.x;
    if (idx >= total) return;
    const int co5 = idx / 2304;
    const int kk  = idx - co5 * 2304;
    const int rs = kk >> 8, ci = kk & 255;
    splitf(W[(co5 * 256 + ci) * 9 + rs], wh[idx], wl[idx]);
}

__global__ void w1_prep(const float* __restrict__ W, ush* __restrict__ wh,
                        ush* __restrict__ wl, int Cin, int Kp, int Cout, int total) {
    const int idx = blockIdx.x * 256 + threadIdx.x;
    if (idx >= total) return;
    const int co = idx / Kp;
    const int k  = idx - co * Kp;
    const float x = (co < Cout && k < Cin) ? W[co * Cin + k] : 0.f;
    splitf(x, wh[idx], wl[idx]);
}

__global__ void in_prep(const float* __restrict__ f, ush* __restrict__ xh,
                        ush* __restrict__ xl, int Cin, int Kp, int logHW, int total) {
    const int idx = blockIdx.x * 256 + threadIdx.x;
    if (idx >= total) return;
    const int c = idx % Kp;
    const int n = idx / Kp;
    const int b  = n >> logHW;
    const int hw = n & ((1 << logHW) - 1);
    const float x = (c < Cin) ? f[((b * Cin + c) << logHW) + hw] : 0.f;
    splitf(x, xh[idx], xl[idx]);
}

__global__ void upsample_hl(ush* __restrict__ fh, ush* __restrict__ fl,
                            const ush* __restrict__ ch, const ush* __restrict__ cl2,
                            int logSf, int total) {
    const int idx = blockIdx.x * 256 + threadIdx.x;
    if (idx >= total) return;
    const int ci = idx & 255;
    const int r  = idx >> 8;
    const int Sf = 1 << logSf;
    const int wf = r & (Sf - 1);
    const int hf = (r >> logSf) & (Sf - 1);
    const int b  = r >> (2 * logSf);
    const int Pf = Sf + 2, Pc = (Sf >> 1) + 2;
    const int fi = ((b * Pf + hf + 1) * Pf + wf + 1) * 256 + ci;
    const int cx = ((b * Pc + (hf >> 1) + 1) * Pc + (wf >> 1) + 1) * 256 + ci;
    const float x = bf2f(fh[fi]) + bf2f(fl[fi]) + bf2f(ch[cx]) + bf2f(cl2[cx]);
    splitf(x, fh[fi], fl[fi]);
}

__global__ void ring_zero(ush* __restrict__ yh, ush* __restrict__ yl, int S, int total) {
    const int idx = blockIdx.x * 256 + threadIdx.x;
    if (idx >= total) return;
    const int ci = idx & 255;
    const int r  = idx >> 8;
    const int P = S + 2;
    const int ring = 4 * P - 4;
    const int pr = r % ring;
    const int b  = r / ring;
    int ph, pw;
    if (pr < P)            { ph = 0;     pw = pr; }
    else if (pr < 2 * P)   { ph = P - 1; pw = pr - P; }
    else { const int q = pr - 2 * P; ph = 1 + (q >> 1); pw = (q & 1) ? (P - 1) : 0; }
    const int a = ((b * P + ph) * P + pw) * 256 + ci;
    yh[a] = 0; yl[a] = 0;
}

// ---------------------------------------------------------------------------

extern "C" void kernel_launch(void* const* d_in, const int* in_sizes, int n_in,
                              void* d_out, int out_size, void* d_ws, size_t ws_size,
                              hipStream_t stream)
{
    const float* f[5];     const float* lat_w[5];
    for (int i = 0; i < 5; ++i) f[i] = (const float*)d_in[i];
    for (int i = 0; i < 5; ++i) lat_w[i] = (const float*)d_in[5 + i];
    const float* lat_b  = (const float*)d_in[10];
    const float* fpn_w  = (const float*)d_in[11];
    const float* fpn_b  = (const float*)d_in[12];
    const float* cls_w1 = (const float*)d_in[13];
    const float* cls_b1 = (const float*)d_in[14];
    const float* cls_g  = (const float*)d_in[15];
    const float* cls_bt = (const float*)d_in[16];
    const float* cls_m  = (const float*)d_in[17];
    const float* cls_v  = (const float*)d_in[18];
    const float* cls_w2 = (const float*)d_in[19];
    const float* cls_b2 = (const float*)d_in[20];
    const float* reg_w1 = (const float*)d_in[21];
    const float* reg_b1 = (const float*)d_in[22];
    const float* reg_g  = (const float*)d_in[23];
    const float* reg_bt = (const float*)d_in[24];
    const float* reg_m  = (const float*)d_in[25];
    const float* reg_v  = (const float*)d_in[26];
    const float* reg_w2 = (const float*)d_in[27];
    const float* reg_b2 = (const float*)d_in[28];

    float* out = (float*)d_out;
    ush*   ws16 = (ush*)d_ws;

    static const int S_[5]     = {128, 64, 32, 16, 8};
    static const int logS_[5]  = {7, 6, 5, 4, 3};
    static const int logHW_[5] = {14, 12, 10, 8, 6};
    static const int HW_[5]    = {16384, 4096, 1024, 256, 64};
    static const int Cin_[5]   = {32, 48, 96, 136, 232};
    static const int Kp_[5]    = {32, 64, 96, 160, 256};
    static const int abase_[5] = {0, 147456, 184320, 193536, 195840};
    constexpr int BIG = 0x7fffffff;

    size_t off = 0;
    auto alloc = [&](size_t elems) {
        ush* p = ws16 + off;
        off += (elems + 63) & ~(size_t)63;
        return p;
    };

    // --- persistent: padded lateral planes (reused as head-conv1 tmp) ---
    ush *lat_h[5], *lat_l[5];
    for (int i = 0; i < 5; ++i) {
        const int P = S_[i] + 2;
        const size_t e = (size_t)2048 * P * P;   // 8 images * P*P * 256
        lat_h[i] = alloc(e); lat_l[i] = alloc(e);
    }
    const size_t lat_bytes = off * sizeof(ush);

    // --- shared transient arena (69.2 MB) ---
    const size_t ARENA_E = (size_t)2 * 4 * 130 * 130 * 256;
    ush* arena = alloc(ARENA_E);

    // --- weights (head conv2 padded to 128 co-rows for unguarded DMA) ---
    ush* fw_h = alloc((size_t)5 * 256 * 2304); ush* fw_l = alloc((size_t)5 * 256 * 2304);
    ush* cw_h = alloc(256 * 2304);             ush* cw_l = alloc(256 * 2304);
    ush* rw_h = alloc(256 * 2304);             ush* rw_l = alloc(256 * 2304);
    ush *lw_h[5], *lw_l[5];
    for (int i = 0; i < 5; ++i) { lw_h[i] = alloc(256 * Kp_[i]); lw_l[i] = alloc(256 * Kp_[i]); }
    ush* c2_h = alloc(128 * 256); ush* c2_l = alloc(128 * 256);
    ush* r2_h = alloc(128 * 256); ush* r2_l = alloc(128 * 256);

    hipMemsetAsync(ws16, 0, lat_bytes, stream);

    // --- weight prep ---
    {
        int t = 5 * 256 * 2304;
        w3_prep<<<dim3((t + 255) / 256), 256, 0, stream>>>(fpn_w, fw_h, fw_l, t);
        t = 256 * 2304;
        w3_prep<<<dim3((t + 255) / 256), 256, 0, stream>>>(cls_w1, cw_h, cw_l, t);
        w3_prep<<<dim3((t + 255) / 256), 256, 0, stream>>>(reg_w1, rw_h, rw_l, t);
        for (int i = 0; i < 5; ++i) {
            t = 256 * Kp_[i];
            w1_prep<<<dim3((t + 255) / 256), 256, 0, stream>>>(lat_w[i], lw_h[i], lw_l[i], Cin_[i], Kp_[i], 256, t);
        }
        t = 128 * 256;
        w1_prep<<<dim3((t + 255) / 256), 256, 0, stream>>>(cls_w2, c2_h, c2_l, 256, 256, 90, t);
        w1_prep<<<dim3((t + 255) / 256), 256, 0, stream>>>(reg_w2, r2_h, r2_l, 256, 256, 36, t);
    }

    // --- input conversion + lateral 1x1 convs (arena transient) ---
    for (int i = 0; i < 5; ++i) {
        const int N = 8 * HW_[i];
        const int t = N * Kp_[i];
        ush* xh = arena;
        ush* xl = arena + (size_t)N * Kp_[i];
        in_prep<<<dim3((t + 255) / 256), 256, 0, stream>>>(f[i], xh, xl, Cin_[i], Kp_[i], logHW_[i], t);
        conv_mfma<1, 0, false, 0><<<dim3(N / 128, 2), 256, 0, stream>>>(
            xh, xl, lw_h[i], lw_l[i], lat_b + i * 256,
            lat_h[i], lat_l[i],
            Kp_[i], logS_[i], logHW_[i], Kp_[i]);
    }

    // --- top-down pathway ---
    for (int i = 4; i >= 1; --i) {
        const int t = 8 * HW_[i - 1] * 256;
        upsample_hl<<<dim3((t + 255) / 256), 256, 0, stream>>>(
            lat_h[i - 1], lat_l[i - 1], lat_h[i], lat_l[i], logS_[i - 1], t);
    }

    // --- levels 1..4 FUSED: all 4 fpn plane pairs resident in arena ---
    ush *fpn_h4[5], *fpn_l4[5];
    {
        size_t o = 0;
        for (int i = 1; i < 5; ++i) {
            const int P = S_[i] + 2;
            fpn_h4[i] = arena + o; o += (size_t)2048 * P * P;
            fpn_l4[i] = arena + o; o += (size_t)2048 * P * P;
        }
    }
    for (int i = 1; i < 5; ++i) {
        const int P = S_[i] + 2;
        const int rt = 8 * (4 * P - 4) * 256;
        ring_zero<<<dim3((rt + 255) / 256), 256, 0, stream>>>(fpn_h4[i], fpn_l4[i], S_[i], rt);
    }
    static const int bstart4[4] = {0, 128, 160, 168};   // 128+32+8+2 = 170 (256px blocks)
    static const int bstartS[4] = {0, 256, 320, 336};   // 340 (128px blocks, conv_sf)

    {   // fused fpn conv (per-level weight slice + bias)
        Tab3 T{};
        for (int k = 0; k < 4; ++k) {
            const int i = k + 1;
            T.l[k] = Lvl3{ lat_h[i], lat_l[i], fpn_h4[i], fpn_l4[i],
                           fpn_b + i * 256, i * 256 * 2304,
                           logS_[i], logHW_[i], bstart4[k] };
        }
        conv3g<0, false><<<dim3(170), 512, 0, stream>>>(
            T, fw_h, fw_l, nullptr, nullptr, nullptr, nullptr);
    }
    {   // fused cls conv1 -> tmp (lat planes)
        Tab3 T{};
        for (int k = 0; k < 4; ++k) {
            const int i = k + 1;
            T.l[k] = Lvl3{ fpn_h4[i], fpn_l4[i], lat_h[i], lat_l[i],
                           cls_b1, 0, logS_[i], logHW_[i], bstart4[k] };
        }
        conv3g<1, true><<<dim3(170), 512, 0, stream>>>(
            T, cw_h, cw_l, cls_g, cls_bt, cls_m, cls_v);
    }
    {   // fused cls conv2 scatter
        TabS T{};
        for (int k = 0; k < 4; ++k) {
            const int i = k + 1;
            T.l[k] = LvlS{ lat_h[i], lat_l[i], abase_[i], logHW_[i], bstartS[k], 0 };
        }
        conv_sf<10><<<dim3(340), 256, 0, stream>>>(T, c2_h, c2_l, cls_b2, out);
    }
    {   // fused reg conv1 -> tmp
        Tab3 T{};
        for (int k = 0; k < 4; ++k) {
            const int i = k + 1;
            T.l[k] = Lvl3{ fpn_h4[i], fpn_l4[i], lat_h[i], lat_l[i],
                           reg_b1, 0, logS_[i], logHW_[i], bstart4[k] };
        }
        conv3g<1, true><<<dim3(170), 512, 0, stream>>>(
            T, rw_h, rw_l, reg_g, reg_bt, reg_m, reg_v);
    }
    {   // fused reg conv2 scatter
        TabS T{};
        for (int k = 0; k < 4; ++k) {
            const int i = k + 1;
            T.l[k] = LvlS{ lat_h[i], lat_l[i], abase_[i], logHW_[i], bstartS[k], 0 };
        }
        conv_sf<4><<<dim3(340), 256, 0, stream>>>(T, r2_h, r2_l, reg_b2, out);
    }

    // --- level 0: two 4-image groups (1-entry tables; 256 blocks = 1 round) ---
    {
        const int P = 130;
        const size_t padg = (size_t)4 * P * P * 256;     // padded, 4 images
        const size_t unpg = (size_t)4 * 16384 * 256;     // unpadded, 4 images
        for (int g = 0; g < 2; ++g) {
            ush* fpn_h = arena;
            ush* fpn_l = arena + padg;
            ush* lat0p_h = lat_h[0] + (size_t)g * padg;
            ush* lat0p_l = lat_l[0] + (size_t)g * padg;
            ush* tmp_h   = lat_h[0] + (size_t)g * unpg;
            ush* tmp_l   = lat_l[0] + (size_t)g * unpg;
            const int rt = 4 * (4 * P - 4) * 256;
            ring_zero<<<dim3((rt + 255) / 256), 256, 0, stream>>>(fpn_h, fpn_l, 128, rt);

            Tab3 T{};
            T.l[0] = Lvl3{ lat0p_h, lat0p_l, fpn_h, fpn_l, fpn_b, 0, 7, 14, 0 };
            for (int k = 1; k < 4; ++k) T.l[k].bstart = BIG;
            conv3g<0, false><<<dim3(256), 512, 0, stream>>>(
                T, fw_h, fw_l, nullptr, nullptr, nullptr, nullptr);

            Tab3 Tc{};
            Tc.l[0] = Lvl3{ fpn_h, fpn_l, tmp_h, tmp_l, cls_b1, 0, 7, 14, 0 };
            for (int k = 1; k < 4; ++k) Tc.l[k].bstart = BIG;
            conv3g<1, true><<<dim3(256), 512, 0, stream>>>(
                Tc, cw_h, cw_l, cls_g, cls_bt, cls_m, cls_v);

            TabS Ts{};
            Ts.l[0] = LvlS{ tmp_h, tmp_l, 0, 14, 0, 4 * g };
            for (int k = 1; k < 4; ++k) Ts.l[k].bstart = BIG;
            conv_sf<10><<<dim3(512), 256, 0, stream>>>(Ts, c2_h, c2_l, cls_b2, out);

            Tab3 Tr{};
            Tr.l[0] = Lvl3{ fpn_h, fpn_l, tmp_h, tmp_l, reg_b1, 0, 7, 14, 0 };
            for (int k = 1; k < 4; ++k) Tr.l[k].bstart = BIG;
            conv3g<1, true><<<dim3(256), 512, 0, stream>>>(
                Tr, rw_h, rw_l, reg_g, reg_bt, reg_m, reg_v);

            TabS Tq{};
            Tq.l[0] = LvlS{ tmp_h, tmp_l, 0, 14, 0, 4 * g };
            for (int k = 1; k < 4; ++k) Tq.l[k].bstart = BIG;
            conv_sf<4><<<dim3(512), 256, 0, stream>>>(Tq, r2_h, r2_l, reg_b2, out);
        }
    }
}

// Round 9
// 2420.924 us; speedup vs baseline: 1.0022x; 1.0022x over previous
//
#include <hip/hip_runtime.h>

// ---------------------------------------------------------------------------
// EfficientDet head on MFMA (gfx950), split-bf16 (hi+lo) fp32-accurate GEMM.
// All convs = implicit GEMM: C[co][n] = W[co][k] * Im2col[k][n].
// Activations: NHWC bf16 hi/lo planes; 3x3 inputs spatially zero-padded P=S+2.
// K order for 3x3: k = (r*3+s)*256 + ci  (tap-major -> contiguous ci chunks).
// 3 MFMAs per tile-pair: AhiBhi + AhiBlo + AloBhi  (error ~2^-17 relative).
//
// R9 == R8 resubmitted (round-8 bench was an infra container failure, not a
// kernel verdict; sync structure re-audited: wave-uniform barrier counts,
// safe buffer lifecycle, addressing unchanged from passing R7).
//
// conv3g = m201-faithful barrier-disciplined 4-phase chunk. Each phase:
// {ds_read frags; issue stage pair; s_barrier; lgkmcnt(0); setprio(1);
// 24 MFMA; setprio(0); s_barrier}. Phases: (A-half0 + B-pair0), (B-pair1),
// (A-half1), (none) — B pairs live all chunk, A-half slot reused; 24
// ds_read_b128/wave/chunk. Stage spread 2/2/4 over phases 1-3 so the
// chunk-boundary vmcnt(0) drains loads issued >=1 phase (~1600cyc) earlier.
// Strict-alternation model: LDS 2304 + MFMA 3725 + barriers ~400 = 6450cyc
// vs R6's 7367 (m201 measured 62% MfmaUtil with this discipline at the
// same 256^2 / 8-wave / 128x64-wave-tile geometry).
// 1x1 lateral + head-scatter convs keep the R1 128^2 global_load_lds kernel.
// ---------------------------------------------------------------------------

typedef unsigned short ush;
typedef __attribute__((ext_vector_type(8))) short v8s;
typedef __attribute__((ext_vector_type(4))) float v4f;

constexpr int TOTAL_ANCH = 196416;  // 9 * (128^2+64^2+32^2+16^2+8^2)

#define VMW(n) asm volatile("s_waitcnt vmcnt(" #n ")" ::: "memory")
#define LGK(n) asm volatile("s_waitcnt lgkmcnt(" #n ")" ::: "memory")
#define SB0()  __builtin_amdgcn_sched_barrier(0)

__device__ __forceinline__ ush f2bf(float x) {
    unsigned u = __builtin_bit_cast(unsigned, x);
    u += 0x7FFFu + ((u >> 16) & 1u);
    return (ush)(u >> 16);
}
__device__ __forceinline__ float bf2f(ush h) {
    unsigned u = ((unsigned)h) << 16;
    return __builtin_bit_cast(float, u);
}
__device__ __forceinline__ void splitf(float x, ush& hi, ush& lo) {
    hi = f2bf(x);
    lo = f2bf(x - bf2f(hi));
}

__device__ __forceinline__ void gl_lds16(const ush* g, short* l) {
    __builtin_amdgcn_global_load_lds(
        (const __attribute__((address_space(1))) unsigned*)(const void*)g,
        (__attribute__((address_space(3))) unsigned*)l, 16, 0, 0);
}

// per-level work descriptors (kernel args by value)
struct Lvl3 {
    const ush* xh; const ush* xl;    // input planes (padded NHWC hi/lo)
    ush* yh; ush* yl;                // output planes
    const float* bias;
    int wofs, logS, logHW, bstart;   // weight elem offset; block range start
};
struct Tab3 { Lvl3 l[4]; };

struct LvlS {
    const ush* xh; const ush* xl;    // input planes (unpadded NHWC hi/lo)
    int abase, logHW, bstart, ibase;
};
struct TabS { LvlS l[4]; };

// ---------------------------------------------------------------------------
// conv3g: deep 3x3 conv, fused multi-level. K=2304, Cout=256, 256 px/block.
// 8 waves: wm=w&1 (co half, 128 rows), wn=w>>1 (px quarter, 64 cols).
// LDS buffer (64KB): Ah[256][32] | Al | Bh[256][32] | Bl (8192 shorts each).
// Staging: role=w>>1 (0:Ah 1:Al 2:Bh 3:Bl), part=w&1 (128-row half); every
// wave 8 x gl_lds16 per chunk. Slot swizzle (both sides, proven 0-conflict):
// seg(row,slot) = slot ^ ((row>>1)&3).
// OM: 0 = padded NHWC hi/lo out; 1 = unpadded NHWC hi/lo out.  BNR: BN+ReLU.
// ---------------------------------------------------------------------------
#define MFMA3(AH, AL, BH, BL, ACC)                                            \
    ACC = __builtin_amdgcn_mfma_f32_16x16x32_bf16(AH, BH, ACC, 0, 0, 0);      \
    ACC = __builtin_amdgcn_mfma_f32_16x16x32_bf16(AH, BL, ACC, 0, 0, 0);      \
    ACC = __builtin_amdgcn_mfma_f32_16x16x32_bf16(AL, BH, ACC, 0, 0, 0);

// read A half H (rows H*64 .. H*64+63 of the wave's 128) into a_h/a_l
#define RDA(H, BP)                                                            \
    _Pragma("unroll")                                                         \
    for (int i = 0; i < 4; ++i) {                                             \
        a_h[i] = *(const v8s*)((BP) + abA + ((H)*4 + i) * 512);               \
        a_l[i] = *(const v8s*)((BP) + abA + 8192 + ((H)*4 + i) * 512);        \
    }

// read B pair {J0, J0+1} into b_h/b_l (held live for the whole chunk)
#define RDB2(J0, BP)                                                          \
    _Pragma("unroll")                                                         \
    for (int j = 0; j < 2; ++j) {                                             \
        b_h[(J0)+j] = *(const v8s*)((BP) + abB + ((J0)+j) * 512);             \
        b_l[(J0)+j] = *(const v8s*)((BP) + abB + 8192 + ((J0)+j) * 512);      \
    }

// 24 MFMAs: current A-half (acc rows IB..IB+3) x B pair {J0,J0+1}
#define MF24(IB, J0)                                                          \
    __builtin_amdgcn_s_setprio(1);                                            \
    _Pragma("unroll")                                                         \
    for (int j = 0; j < 2; ++j) {                                             \
        _Pragma("unroll")                                                     \
        for (int i = 0; i < 4; ++i) {                                         \
            MFMA3(a_h[i], a_l[i], b_h[(J0)+j], b_l[(J0)+j],                   \
                  acc[(IB)+i][(J0)+j]);                                       \
        }                                                                     \
    }                                                                         \
    __builtin_amdgcn_s_setprio(0);

template <int OM, bool BNR>
__global__ __launch_bounds__(512, 2)
void conv3g(Tab3 T,
            const ush* __restrict__ Wh, const ush* __restrict__ Wl,
            const float* __restrict__ bng, const float* __restrict__ bnb,
            const float* __restrict__ bnm, const float* __restrict__ bnv)
{
    constexpr int K = 2304, KC = 72;
    constexpr int BUFS = 32768;   // shorts per buffer (64KB)

    // bijective XCD-aware swizzle on the 1-D grid
    const int nwg = gridDim.x;
    const int flat = blockIdx.x;
    const int xcd = flat & 7, sidx = flat >> 3;
    const int q = nwg >> 3, r8 = nwg & 7;
    const int nf = (xcd < r8 ? xcd * (q + 1) : r8 * (q + 1) + (xcd - r8) * q) + sidx;

    // level lookup
    int li = 0;
    if (nf >= T.l[1].bstart) li = 1;
    if (nf >= T.l[2].bstart) li = 2;
    if (nf >= T.l[3].bstart) li = 3;
    const int logS = T.l[li].logS, logHW = T.l[li].logHW;
    const int S = 1 << logS, HW = 1 << logHW, P = S + 2;
    const ush* __restrict__ Xh = T.l[li].xh;
    const ush* __restrict__ Xl = T.l[li].xl;
    ush* __restrict__ Yh = T.l[li].yh;
    ush* __restrict__ Yl = T.l[li].yl;
    const float* __restrict__ bias = T.l[li].bias;
    const int wofs = T.l[li].wofs;
    const int n0 = (nf - T.l[li].bstart) * 256;

    __shared__ __align__(16) short lds[2][BUFS];
    // buffer layout (shorts): Ah 0 | Al 8192 | Bh 16384 | Bl 24576

    const int tid = threadIdx.x;
    const int lane = tid & 63, w = tid >> 6;
    const int wm = w & 1, wn = w >> 1;       // wave tile: 128 co x 64 px
    const int l15 = lane & 15, l4 = lane >> 4;
    const int lr = lane >> 2, ls = lane & 3;
    const int sw = ls ^ ((lr >> 1) & 3);

    const int role = w >> 1, part = w & 1;   // 0:Ah 1:Al 2:Bh 3:Bl
    const ush* gsrc = role == 0 ? Wh + wofs : role == 1 ? Wl + wofs
                    : role == 2 ? Xh : Xl;
    const int poff = role * 8192 + part * 4096;

    int sb[8];
    if (role < 2) {
#pragma unroll
        for (int t = 0; t < 8; ++t)
            sb[t] = (part * 128 + t * 16 + lr) * K + sw * 8;
    } else {
#pragma unroll
        for (int t = 0; t < 8; ++t) {
            const int p = n0 + part * 128 + t * 16 + lr;
            const int bb = p >> logHW, hw = p & (HW - 1);
            const int oh = hw >> logS, ow = hw & (S - 1);
            sb[t] = ((bb * P + oh + 1) * P + ow + 1) * 256 + sw * 8;
        }
    }

    // stage loads [t0, t0+nt) of chunk c into buffer u
    auto stage_g = [&](int u, int c, int t0, int nt) {
        short* db = &lds[0][0] + u * BUFS + poff;
        int coff;
        if (role < 2) coff = c * 32;
        else {
            const int rs = c >> 3;             // tap 0..8 (uniform)
            const int rr = (rs * 11) >> 5;     // rs / 3
            const int ss = rs - 3 * rr;
            coff = ((rr - 1) * P + (ss - 1)) * 256 + (c & 7) * 32;
        }
        for (int t = t0; t < t0 + nt; ++t)
            gl_lds16(gsrc + (sb[t] + coff), db + t * 512);
    };

    // fragment base offsets within a buffer (shorts); per-i/j step = 512
    const int slr = (l4 ^ ((l15 >> 1) & 3)) * 8;
    const int abA = (wm * 128 + l15) * 32 + slr;
    const int abB = 16384 + (wn * 64 + l15) * 32 + slr;

    v4f acc[8][4] = {};
    v8s a_h[4], a_l[4];       // current A half (slot reused: half0 then half1)
    v8s b_h[4], b_l[4];       // all 4 B columns, live across the chunk

    // prologue: chunk 0 staged; wait + barrier
    stage_g(0, 0, 0, 8);
    VMW(0);
    SB0();
    __builtin_amdgcn_s_barrier();

    int cur = 0;
    for (int c = 0; c < KC; ++c) {
        const bool pf = (c + 1) < KC;
        const short* bp = &lds[0][0] + cur * BUFS;
        const int nxt = cur ^ 1;

        // ---- phase 1: read A half0 (8) + B pair0 (4); stage 2 ----
        RDA(0, bp); RDB2(0, bp);
        if (pf) stage_g(nxt, c + 1, 0, 2);
        __builtin_amdgcn_s_barrier();
        LGK(0); SB0();
        MF24(0, 0);
        __builtin_amdgcn_s_barrier();

        // ---- phase 2: read B pair1 (4); stage 2 ----
        RDB2(2, bp);
        if (pf) stage_g(nxt, c + 1, 2, 2);
        __builtin_amdgcn_s_barrier();
        LGK(0); SB0();
        MF24(0, 2);
        __builtin_amdgcn_s_barrier();

        // ---- phase 3: read A half1 (8, reuses slot); stage 4 ----
        RDA(1, bp);
        if (pf) stage_g(nxt, c + 1, 4, 4);
        __builtin_amdgcn_s_barrier();
        LGK(0); SB0();
        MF24(4, 2);
        __builtin_amdgcn_s_barrier();

        // ---- phase 4: no reads; B pair0 + A half1 ----
        SB0();
        MF24(4, 0);
        // boundary: drain next chunk's DMA (last issued >=1 phase ago)
        if (pf) VMW(0);
        SB0();
        __builtin_amdgcn_s_barrier();
        cur ^= 1;
    }

    // ---- epilogue: col = lane&15 (pixel), row = (lane>>4)*4+e (co) ----
#pragma unroll
    for (int i = 0; i < 8; ++i) {
        const int co = wm * 128 + i * 16 + l4 * 4;
        float sc[4], sh[4];
#pragma unroll
        for (int e = 0; e < 4; ++e) {
            if (BNR) {
                const float inv = bng[co + e] * rsqrtf(bnv[co + e] + 1e-5f);
                sc[e] = inv;
                sh[e] = (bias[co + e] - bnm[co + e]) * inv + bnb[co + e];
            } else { sc[e] = 1.f; sh[e] = bias[co + e]; }
        }
#pragma unroll
        for (int j = 0; j < 4; ++j) {
            const int ncol = n0 + wn * 64 + j * 16 + l15;
            const int b  = ncol >> logHW;
            const int hw = ncol & (HW - 1);
            float val[4];
#pragma unroll
            for (int e = 0; e < 4; ++e) {
                float x = acc[i][j][e] * sc[e] + sh[e];
                if (BNR) x = fmaxf(x, 0.f);
                val[e] = x;
            }
            int pidx;
            if (OM == 0) {
                const int oh = hw >> logS, ow = hw & (S - 1);
                pidx = (b * P + oh + 1) * P + ow + 1;
            } else {
                pidx = ncol;
            }
            const int addr = pidx * 256 + co;
            ush hs[4], ls2[4];
#pragma unroll
            for (int e = 0; e < 4; ++e) splitf(val[e], hs[e], ls2[e]);
            *(uint2*)&Yh[addr] = make_uint2(hs[0] | ((unsigned)hs[1] << 16),
                                            hs[2] | ((unsigned)hs[3] << 16));
            *(uint2*)&Yl[addr] = make_uint2(ls2[0] | ((unsigned)ls2[1] << 16),
                                            ls2[2] | ((unsigned)ls2[3] << 16));
        }
    }
}

// ---------------------------------------------------------------------------
// Fused scatter head-conv2 (1x1, K=256, Cout=9*DD, fp32 scatter epilogue).
// 4 waves, 128 px/block, co0 = 0 (Cout <= 128; weights zero-padded to 128).
// ---------------------------------------------------------------------------
template <int DD>
__global__ __launch_bounds__(256, 3)
void conv_sf(TabS T, const ush* __restrict__ Wh, const ush* __restrict__ Wl,
             const float* __restrict__ bias, float* __restrict__ out)
{
    constexpr int K = 256, KC = 8, Cout = 9 * DD;
    constexpr int coloff = (DD == 10) ? 4 : 0;

    const int nwg = gridDim.x;
    const int flat = blockIdx.x;
    const int xcd = flat & 7, sidx = flat >> 3;
    const int q = nwg >> 3, r8 = nwg & 7;
    const int nf = (xcd < r8 ? xcd * (q + 1) : r8 * (q + 1) + (xcd - r8) * q) + sidx;

    int li = 0;
    if (nf >= T.l[1].bstart) li = 1;
    if (nf >= T.l[2].bstart) li = 2;
    if (nf >= T.l[3].bstart) li = 3;
    const int logHW = T.l[li].logHW;
    const int HW = 1 << logHW;
    const ush* __restrict__ Xh = T.l[li].xh;
    const ush* __restrict__ Xl = T.l[li].xl;
    const int abase = T.l[li].abase, ibase = T.l[li].ibase;
    const int n0 = (nf - T.l[li].bstart) * 128;

    __shared__ short lds[4][128][32];

    const int tid = threadIdx.x;
    const int lane = tid & 63;
    const int w = tid >> 6;
    const int wm = w & 1, wn = w >> 1;
    const int l15 = lane & 15, l4 = lane >> 4;
    const int lr = lane >> 2, ls = lane & 3;
    const int sw = ls ^ ((lr >> 1) & 3);
    const ush* gsrc = (w == 0) ? Wh : (w == 1) ? Wl : (w == 2) ? Xh : Xl;
    int sb[8];
    if (w < 2) {
#pragma unroll
        for (int t = 0; t < 8; ++t)
            sb[t] = (t * 16 + lr) * K + sw * 8;
    } else {
#pragma unroll
        for (int t = 0; t < 8; ++t)
            sb[t] = (n0 + t * 16 + lr) * 256 + sw * 8;
    }
    short* mypl = &lds[w][0][0];
    const int slA = (l4 ^ ((l15 >> 1) & 3)) * 8;

    v4f acc[4][4] = {};

    for (int c = 0; c < KC; ++c) {
        const int coff = c * 32;
#pragma unroll
        for (int t = 0; t < 8; ++t)
            gl_lds16(gsrc + (sb[t] + coff), mypl + t * 512);

        __syncthreads();

        v8s ah[4], al[4];
#pragma unroll
        for (int i = 0; i < 4; ++i) {
            ah[i] = *(const v8s*)&lds[0][wm * 64 + i * 16 + l15][slA];
            al[i] = *(const v8s*)&lds[1][wm * 64 + i * 16 + l15][slA];
        }
#pragma unroll
        for (int j = 0; j < 4; ++j) {
            const v8s bh = *(const v8s*)&lds[2][wn * 64 + j * 16 + l15][slA];
            const v8s bl = *(const v8s*)&lds[3][wn * 64 + j * 16 + l15][slA];
#pragma unroll
            for (int i = 0; i < 4; ++i) {
                acc[i][j] = __builtin_amdgcn_mfma_f32_16x16x32_bf16(ah[i], bh, acc[i][j], 0, 0, 0);
                acc[i][j] = __builtin_amdgcn_mfma_f32_16x16x32_bf16(ah[i], bl, acc[i][j], 0, 0, 0);
                acc[i][j] = __builtin_amdgcn_mfma_f32_16x16x32_bf16(al[i], bh, acc[i][j], 0, 0, 0);
            }
        }
        __syncthreads();
    }

#pragma unroll
    for (int i = 0; i < 4; ++i) {
        const int co = wm * 64 + i * 16 + l4 * 4;
        float sh[4];
#pragma unroll
        for (int e = 0; e < 4; ++e)
            sh[e] = (co + e < Cout) ? bias[co + e] : 0.f;
#pragma unroll
        for (int j = 0; j < 4; ++j) {
            const int ncol = n0 + wn * 64 + j * 16 + l15;
            const int b  = ncol >> logHW;
            const int hw = ncol & (HW - 1);
#pragma unroll
            for (int e = 0; e < 4; ++e) {
                const int c2 = co + e;
                if (c2 < Cout) {
                    const float val = acc[i][j][e] + sh[e];
                    const int a = c2 / DD, cl = c2 - a * DD;
                    out[(size_t)((b + ibase) * TOTAL_ANCH + abase + hw * 9 + a) * 14
                        + coloff + cl] = val;
                }
            }
        }
    }
}

// ---------------------------------------------------------------------------
// R1 128^2 kernel — retained for the 1x1 lateral convs (KS=1, OM=0).
// ---------------------------------------------------------------------------
template <int KS, int OM, bool BNR, int DD>
__global__ __launch_bounds__(256, 3)
void conv_mfma(const ush* __restrict__ Xh, const ush* __restrict__ Xl,
               const ush* __restrict__ Wh, const ush* __restrict__ Wl,
               const float* __restrict__ bias,
               ush* __restrict__ Yh, ush* __restrict__ Yl,
               int K, int logS, int logHW, int Kin)
{
    const int tid = threadIdx.x;

    const int nwg  = gridDim.x * gridDim.y;
    const int flat = blockIdx.y * gridDim.x + blockIdx.x;
    const int xcd = flat & 7, sidx = flat >> 3;
    const int q = nwg >> 3, r8 = nwg & 7;
    const int nf = (xcd < r8 ? xcd * (q + 1) : r8 * (q + 1) + (xcd - r8) * q) + sidx;
    int bx, by;
    if (gridDim.y == 2) { bx = nf >> 1; by = nf & 1; }
    else                { bx = nf;      by = 0;      }

    const int n0  = bx * 128;
    const int co0 = by * 128;
    const int S = 1 << logS, HW = 1 << logHW, P = S + 2;

    __shared__ short lds[4][128][32];

    const int lane = tid & 63;
    const int w = tid >> 6;
    const int wm = w & 1, wn = w >> 1;
    const int l15 = lane & 15, l4 = lane >> 4;

    const int lr = lane >> 2, ls = lane & 3;
    const int sw = ls ^ ((lr >> 1) & 3);
    const ush* gsrc = (w == 0) ? Wh : (w == 1) ? Wl : (w == 2) ? Xh : Xl;
    int sb[8];
    if (w < 2) {
#pragma unroll
        for (int t = 0; t < 8; ++t)
            sb[t] = (co0 + t * 16 + lr) * K + sw * 8;
    } else {
#pragma unroll
        for (int t = 0; t < 8; ++t) {
            const int p = n0 + t * 16 + lr;
            sb[t] = p * Kin + sw * 8;
        }
    }
    short* mypl = &lds[w][0][0];

    const int KC = K >> 5;
    const int slA = (l4 ^ ((l15 >> 1) & 3)) * 8;

    v4f acc[4][4] = {};

    for (int c = 0; c < KC; ++c) {
        const int coff = c * 32;
#pragma unroll
        for (int t = 0; t < 8; ++t)
            gl_lds16(gsrc + (sb[t] + coff), mypl + t * 512);

        __syncthreads();

        v8s ah[4], al[4];
#pragma unroll
        for (int i = 0; i < 4; ++i) {
            ah[i] = *(const v8s*)&lds[0][wm * 64 + i * 16 + l15][slA];
            al[i] = *(const v8s*)&lds[1][wm * 64 + i * 16 + l15][slA];
        }
#pragma unroll
        for (int j = 0; j < 4; ++j) {
            const v8s bh = *(const v8s*)&lds[2][wn * 64 + j * 16 + l15][slA];
            const v8s bl = *(const v8s*)&lds[3][wn * 64 + j * 16 + l15][slA];
#pragma unroll
            for (int i = 0; i < 4; ++i) {
                acc[i][j] = __builtin_amdgcn_mfma_f32_16x16x32_bf16(ah[i], bh, acc[i][j], 0, 0, 0);
                acc[i][j] = __builtin_amdgcn_mfma_f32_16x16x32_bf16(ah[i], bl, acc[i][j], 0, 0, 0);
                acc[i][j] = __builtin_amdgcn_mfma_f32_16x16x32_bf16(al[i], bh, acc[i][j], 0, 0, 0);
            }
        }
        __syncthreads();
    }

#pragma unroll
    for (int i = 0; i < 4; ++i) {
        const int cob = wm * 64 + i * 16 + l4 * 4;
        const int co  = co0 + cob;
        float sh[4];
#pragma unroll
        for (int e = 0; e < 4; ++e) sh[e] = bias[co + e];
#pragma unroll
        for (int j = 0; j < 4; ++j) {
            const int ncol = n0 + wn * 64 + j * 16 + l15;
            const int b  = ncol >> logHW;
            const int hw = ncol & (HW - 1);
            float val[4];
#pragma unroll
            for (int e = 0; e < 4; ++e) val[e] = acc[i][j][e] + sh[e];
            int pidx;
            if (OM == 0) {
                const int oh = hw >> logS, ow = hw & (S - 1);
                pidx = (b * P + oh + 1) * P + ow + 1;
            } else {
                pidx = ncol;
            }
            const int addr = pidx * 256 + co;
            ush hs[4], ls2[4];
#pragma unroll
            for (int e = 0; e < 4; ++e) splitf(val[e], hs[e], ls2[e]);
            *(uint2*)&Yh[addr] = make_uint2(hs[0] | ((unsigned)hs[1] << 16),
                                            hs[2] | ((unsigned)hs[3] << 16));
            *(uint2*)&Yl[addr] = make_uint2(ls2[0] | ((unsigned)ls2[1] << 16),
                                            ls2[2] | ((unsigned)ls2[3] << 16));
        }
    }
}

// ---- prep / glue kernels -------------------------------------------------

__global__ void w3_prep(const float* __restrict__ W, ush* __restrict__ wh,
                        ush* __restrict__ wl, int total) {
    const int idx = blockIdx.x * 256 + threadIdx.x;
    if (idx >= total) return;
    const int co5 = idx / 2304;
    const int kk  = idx - co5 * 2304;
    const int rs = kk >> 8, ci = kk & 255;
    splitf(W[(co5 * 256 + ci) * 9 + rs], wh[idx], wl[idx]);
}

__global__ void w1_prep(const float* __restrict__ W, ush* __restrict__ wh,
                        ush* __restrict__ wl, int Cin, int Kp, int Cout, int total) {
    const int idx = blockIdx.x * 256 + threadIdx.x;
    if (idx >= total) return;
    const int co = idx / Kp;
    const int k  = idx - co * Kp;
    const float x = (co < Cout && k < Cin) ? W[co * Cin + k] : 0.f;
    splitf(x, wh[idx], wl[idx]);
}

__global__ void in_prep(const float* __restrict__ f, ush* __restrict__ xh,
                        ush* __restrict__ xl, int Cin, int Kp, int logHW, int total) {
    const int idx = blockIdx.x * 256 + threadIdx.x;
    if (idx >= total) return;
    const int c = idx % Kp;
    const int n = idx / Kp;
    const int b  = n >> logHW;
    const int hw = n & ((1 << logHW) - 1);
    const float x = (c < Cin) ? f[((b * Cin + c) << logHW) + hw] : 0.f;
    splitf(x, xh[idx], xl[idx]);
}

__global__ void upsample_hl(ush* __restrict__ fh, ush* __restrict__ fl,
                            const ush* __restrict__ ch, const ush* __restrict__ cl2,
                            int logSf, int total) {
    const int idx = blockIdx.x * 256 + threadIdx.x;
    if (idx >= total) return;
    const int ci = idx & 255;
    const int r  = idx >> 8;
    const int Sf = 1 << logSf;
    const int wf = r & (Sf - 1);
    const int hf = (r >> logSf) & (Sf - 1);
    const int b  = r >> (2 * logSf);
    const int Pf = Sf + 2, Pc = (Sf >> 1) + 2;
    const int fi = ((b * Pf + hf + 1) * Pf + wf + 1) * 256 + ci;
    const int cx = ((b * Pc + (hf >> 1) + 1) * Pc + (wf >> 1) + 1) * 256 + ci;
    const float x = bf2f(fh[fi]) + bf2f(fl[fi]) + bf2f(ch[cx]) + bf2f(cl2[cx]);
    splitf(x, fh[fi], fl[fi]);
}

__global__ void ring_zero(ush* __restrict__ yh, ush* __restrict__ yl, int S, int total) {
    const int idx = blockIdx.x * 256 + threadIdx.x;
    if (idx >= total) return;
    const int ci = idx & 255;
    const int r  = idx >> 8;
    const int P = S + 2;
    const int ring = 4 * P - 4;
    const int pr = r % ring;
    const int b  = r / ring;
    int ph, pw;
    if (pr < P)            { ph = 0;     pw = pr; }
    else if (pr < 2 * P)   { ph = P - 1; pw = pr - P; }
    else { const int q = pr - 2 * P; ph = 1 + (q >> 1); pw = (q & 1) ? (P - 1) : 0; }
    const int a = ((b * P + ph) * P + pw) * 256 + ci;
    yh[a] = 0; yl[a] = 0;
}

// ---------------------------------------------------------------------------

extern "C" void kernel_launch(void* const* d_in, const int* in_sizes, int n_in,
                              void* d_out, int out_size, void* d_ws, size_t ws_size,
                              hipStream_t stream)
{
    const float* f[5];     const float* lat_w[5];
    for (int i = 0; i < 5; ++i) f[i] = (const float*)d_in[i];
    for (int i = 0; i < 5; ++i) lat_w[i] = (const float*)d_in[5 + i];
    const float* lat_b  = (const float*)d_in[10];
    const float* fpn_w  = (const float*)d_in[11];
    const float* fpn_b  = (const float*)d_in[12];
    const float* cls_w1 = (const float*)d_in[13];
    const float* cls_b1 = (const float*)d_in[14];
    const float* cls_g  = (const float*)d_in[15];
    const float* cls_bt = (const float*)d_in[16];
    const float* cls_m  = (const float*)d_in[17];
    const float* cls_v  = (const float*)d_in[18];
    const float* cls_w2 = (const float*)d_in[19];
    const float* cls_b2 = (const float*)d_in[20];
    const float* reg_w1 = (const float*)d_in[21];
    const float* reg_b1 = (const float*)d_in[22];
    const float* reg_g  = (const float*)d_in[23];
    const float* reg_bt = (const float*)d_in[24];
    const float* reg_m  = (const float*)d_in[25];
    const float* reg_v  = (const float*)d_in[26];
    const float* reg_w2 = (const float*)d_in[27];
    const float* reg_b2 = (const float*)d_in[28];

    float* out = (float*)d_out;
    ush*   ws16 = (ush*)d_ws;

    static const int S_[5]     = {128, 64, 32, 16, 8};
    static const int logS_[5]  = {7, 6, 5, 4, 3};
    static const int logHW_[5] = {14, 12, 10, 8, 6};
    static const int HW_[5]    = {16384, 4096, 1024, 256, 64};
    static const int Cin_[5]   = {32, 48, 96, 136, 232};
    static const int Kp_[5]    = {32, 64, 96, 160, 256};
    static const int abase_[5] = {0, 147456, 184320, 193536, 195840};
    constexpr int BIG = 0x7fffffff;

    size_t off = 0;
    auto alloc = [&](size_t elems) {
        ush* p = ws16 + off;
        off += (elems + 63) & ~(size_t)63;
        return p;
    };

    // --- persistent: padded lateral planes (reused as head-conv1 tmp) ---
    ush *lat_h[5], *lat_l[5];
    for (int i = 0; i < 5; ++i) {
        const int P = S_[i] + 2;
        const size_t e = (size_t)2048 * P * P;   // 8 images * P*P * 256
        lat_h[i] = alloc(e); lat_l[i] = alloc(e);
    }
    const size_t lat_bytes = off * sizeof(ush);

    // --- shared transient arena (69.2 MB) ---
    const size_t ARENA_E = (size_t)2 * 4 * 130 * 130 * 256;
    ush* arena = alloc(ARENA_E);

    // --- weights (head conv2 padded to 128 co-rows for unguarded DMA) ---
    ush* fw_h = alloc((size_t)5 * 256 * 2304); ush* fw_l = alloc((size_t)5 * 256 * 2304);
    ush* cw_h = alloc(256 * 2304);             ush* cw_l = alloc(256 * 2304);
    ush* rw_h = alloc(256 * 2304);             ush* rw_l = alloc(256 * 2304);
    ush *lw_h[5], *lw_l[5];
    for (int i = 0; i < 5; ++i) { lw_h[i] = alloc(256 * Kp_[i]); lw_l[i] = alloc(256 * Kp_[i]); }
    ush* c2_h = alloc(128 * 256); ush* c2_l = alloc(128 * 256);
    ush* r2_h = alloc(128 * 256); ush* r2_l = alloc(128 * 256);

    hipMemsetAsync(ws16, 0, lat_bytes, stream);

    // --- weight prep ---
    {
        int t = 5 * 256 * 2304;
        w3_prep<<<dim3((t + 255) / 256), 256, 0, stream>>>(fpn_w, fw_h, fw_l, t);
        t = 256 * 2304;
        w3_prep<<<dim3((t + 255) / 256), 256, 0, stream>>>(cls_w1, cw_h, cw_l, t);
        w3_prep<<<dim3((t + 255) / 256), 256, 0, stream>>>(reg_w1, rw_h, rw_l, t);
        for (int i = 0; i < 5; ++i) {
            t = 256 * Kp_[i];
            w1_prep<<<dim3((t + 255) / 256), 256, 0, stream>>>(lat_w[i], lw_h[i], lw_l[i], Cin_[i], Kp_[i], 256, t);
        }
        t = 128 * 256;
        w1_prep<<<dim3((t + 255) / 256), 256, 0, stream>>>(cls_w2, c2_h, c2_l, 256, 256, 90, t);
        w1_prep<<<dim3((t + 255) / 256), 256, 0, stream>>>(reg_w2, r2_h, r2_l, 256, 256, 36, t);
    }

    // --- input conversion + lateral 1x1 convs (arena transient) ---
    for (int i = 0; i < 5; ++i) {
        const int N = 8 * HW_[i];
        const int t = N * Kp_[i];
        ush* xh = arena;
        ush* xl = arena + (size_t)N * Kp_[i];
        in_prep<<<dim3((t + 255) / 256), 256, 0, stream>>>(f[i], xh, xl, Cin_[i], Kp_[i], logHW_[i], t);
        conv_mfma<1, 0, false, 0><<<dim3(N / 128, 2), 256, 0, stream>>>(
            xh, xl, lw_h[i], lw_l[i], lat_b + i * 256,
            lat_h[i], lat_l[i],
            Kp_[i], logS_[i], logHW_[i], Kp_[i]);
    }

    // --- top-down pathway ---
    for (int i = 4; i >= 1; --i) {
        const int t = 8 * HW_[i - 1] * 256;
        upsample_hl<<<dim3((t + 255) / 256), 256, 0, stream>>>(
            lat_h[i - 1], lat_l[i - 1], lat_h[i], lat_l[i], logS_[i - 1], t);
    }

    // --- levels 1..4 FUSED: all 4 fpn plane pairs resident in arena ---
    ush *fpn_h4[5], *fpn_l4[5];
    {
        size_t o = 0;
        for (int i = 1; i < 5; ++i) {
            const int P = S_[i] + 2;
            fpn_h4[i] = arena + o; o += (size_t)2048 * P * P;
            fpn_l4[i] = arena + o; o += (size_t)2048 * P * P;
        }
    }
    for (int i = 1; i < 5; ++i) {
        const int P = S_[i] + 2;
        const int rt = 8 * (4 * P - 4) * 256;
        ring_zero<<<dim3((rt + 255) / 256), 256, 0, stream>>>(fpn_h4[i], fpn_l4[i], S_[i], rt);
    }
    static const int bstart4[4] = {0, 128, 160, 168};   // 128+32+8+2 = 170 (256px blocks)
    static const int bstartS[4] = {0, 256, 320, 336};   // 340 (128px blocks, conv_sf)

    {   // fused fpn conv (per-level weight slice + bias)
        Tab3 T{};
        for (int k = 0; k < 4; ++k) {
            const int i = k + 1;
            T.l[k] = Lvl3{ lat_h[i], lat_l[i], fpn_h4[i], fpn_l4[i],
                           fpn_b + i * 256, i * 256 * 2304,
                           logS_[i], logHW_[i], bstart4[k] };
        }
        conv3g<0, false><<<dim3(170), 512, 0, stream>>>(
            T, fw_h, fw_l, nullptr, nullptr, nullptr, nullptr);
    }
    {   // fused cls conv1 -> tmp (lat planes)
        Tab3 T{};
        for (int k = 0; k < 4; ++k) {
            const int i = k + 1;
            T.l[k] = Lvl3{ fpn_h4[i], fpn_l4[i], lat_h[i], lat_l[i],
                           cls_b1, 0, logS_[i], logHW_[i], bstart4[k] };
        }
        conv3g<1, true><<<dim3(170), 512, 0, stream>>>(
            T, cw_h, cw_l, cls_g, cls_bt, cls_m, cls_v);
    }
    {   // fused cls conv2 scatter
        TabS T{};
        for (int k = 0; k < 4; ++k) {
            const int i = k + 1;
            T.l[k] = LvlS{ lat_h[i], lat_l[i], abase_[i], logHW_[i], bstartS[k], 0 };
        }
        conv_sf<10><<<dim3(340), 256, 0, stream>>>(T, c2_h, c2_l, cls_b2, out);
    }
    {   // fused reg conv1 -> tmp
        Tab3 T{};
        for (int k = 0; k < 4; ++k) {
            const int i = k + 1;
            T.l[k] = Lvl3{ fpn_h4[i], fpn_l4[i], lat_h[i], lat_l[i],
                           reg_b1, 0, logS_[i], logHW_[i], bstart4[k] };
        }
        conv3g<1, true><<<dim3(170), 512, 0, stream>>>(
            T, rw_h, rw_l, reg_g, reg_bt, reg_m, reg_v);
    }
    {   // fused reg conv2 scatter
        TabS T{};
        for (int k = 0; k < 4; ++k) {
            const int i = k + 1;
            T.l[k] = LvlS{ lat_h[i], lat_l[i], abase_[i], logHW_[i], bstartS[k], 0 };
        }
        conv_sf<4><<<dim3(340), 256, 0, stream>>>(T, r2_h, r2_l, reg_b2, out);
    }

    // --- level 0: two 4-image groups (1-entry tables; 256 blocks = 1 round) ---
    {
        const int P = 130;
        const size_t padg = (size_t)4 * P * P * 256;     // padded, 4 images
        const size_t unpg = (size_t)4 * 16384 * 256;     // unpadded, 4 images
        for (int g = 0; g < 2; ++g) {
            ush* fpn_h = arena;
            ush* fpn_l = arena + padg;
            ush* lat0p_h = lat_h[0] + (size_t)g * padg;
            ush* lat0p_l = lat_l[0] + (size_t)g * padg;
            ush* tmp_h   = lat_h[0] + (size_t)g * unpg;
            ush* tmp_l   = lat_l[0] + (size_t)g * unpg;
            const int rt = 4 * (4 * P - 4) * 256;
            ring_zero<<<dim3((rt + 255) / 256), 256, 0, stream>>>(fpn_h, fpn_l, 128, rt);

            Tab3 T{};
            T.l[0] = Lvl3{ lat0p_h, lat0p_l, fpn_h, fpn_l, fpn_b, 0, 7, 14, 0 };
            for (int k = 1; k < 4; ++k) T.l[k].bstart = BIG;
            conv3g<0, false><<<dim3(256), 512, 0, stream>>>(
                T, fw_h, fw_l, nullptr, nullptr, nullptr, nullptr);

            Tab3 Tc{};
            Tc.l[0] = Lvl3{ fpn_h, fpn_l, tmp_h, tmp_l, cls_b1, 0, 7, 14, 0 };
            for (int k = 1; k < 4; ++k) Tc.l[k].bstart = BIG;
            conv3g<1, true><<<dim3(256), 512, 0, stream>>>(
                Tc, cw_h, cw_l, cls_g, cls_bt, cls_m, cls_v);

            TabS Ts{};
            Ts.l[0] = LvlS{ tmp_h, tmp_l, 0, 14, 0, 4 * g };
            for (int k = 1; k < 4; ++k) Ts.l[k].bstart = BIG;
            conv_sf<10><<<dim3(512), 256, 0, stream>>>(Ts, c2_h, c2_l, cls_b2, out);

            Tab3 Tr{};
            Tr.l[0] = Lvl3{ fpn_h, fpn_l, tmp_h, tmp_l, reg_b1, 0, 7, 14, 0 };
            for (int k = 1; k < 4; ++k) Tr.l[k].bstart = BIG;
            conv3g<1, true><<<dim3(256), 512, 0, stream>>>(
                Tr, rw_h, rw_l, reg_g, reg_bt, reg_m, reg_v);

            TabS Tq{};
            Tq.l[0] = LvlS{ tmp_h, tmp_l, 0, 14, 0, 4 * g };
            for (int k = 1; k < 4; ++k) Tq.l[k].bstart = BIG;
            conv_sf<4><<<dim3(512), 256, 0, stream>>>(Tq, r2_h, r2_l, reg_b2, out);
        }
    }
}

// Round 10
// 2381.031 us; speedup vs baseline: 1.0190x; 1.0168x over previous
//
#include <hip/hip_runtime.h>

// ---------------------------------------------------------------------------
// EfficientDet head on MFMA (gfx950), split-bf16 (hi+lo) fp32-accurate GEMM.
// All convs = implicit GEMM: C[co][n] = W[co][k] * Im2col[k][n].
// Activations: NHWC bf16 hi/lo planes; 3x3 inputs spatially zero-padded P=S+2.
// K order for 3x3: k = (r*3+s)*256 + ci  (tap-major -> contiguous ci chunks).
// 3 MFMAs per tile-pair: AhiBhi + AhiBlo + AloBhi  (error ~2^-17 relative).
//
// R10: conv3g with CROSS-CHUNK operand prefetch — removes the head-batch
// stall (R6's ~1700cyc: all waves reading chunk operands AFTER the boundary
// barrier). Chunk c enters with A-half0(c)+B01(c) already in regs (read
// during c-1's back phases). One barrier per chunk (mid-sync), all waits
// counted-or-stale:
//  ph1: LGK(0)[free]; issue b23+a1 reads; MFMA(a0 x b01)      rows0-3 c0-1
//  ph2: LGK(8)[b23 landed]; MFMA(a0 x b23)                    rows0-3 c2-3
//  mid: LGK(0)+VMW(0)[DMA(c+1), issued 1 chunk ago]+s_barrier
//       -> buf[nxt] readable, buf[cur] fully consumed (all waves LGK'd)
//  ph3: prefetch A-half0(c+1) into a0 (dead); stage DMA(c+2)->buf[cur]
//       (own-parity buffer); MFMA(a1 x b23)                   rows4-7 c2-3
//  ph4: MFMA(a1 x b01); then prefetch B01(c+1) (anti-dep safe) rows4-7 c0-1
// Per-cell MFMA order and K-order unchanged -> bit-identical numerics.
// 1x1 lateral + head-scatter convs keep the R1 128^2 global_load_lds kernel.
// ---------------------------------------------------------------------------

typedef unsigned short ush;
typedef __attribute__((ext_vector_type(8))) short v8s;
typedef __attribute__((ext_vector_type(4))) float v4f;

constexpr int TOTAL_ANCH = 196416;  // 9 * (128^2+64^2+32^2+16^2+8^2)

#define VMW(n) asm volatile("s_waitcnt vmcnt(" #n ")" ::: "memory")
#define LGK(n) asm volatile("s_waitcnt lgkmcnt(" #n ")" ::: "memory")
#define SB0()  __builtin_amdgcn_sched_barrier(0)

__device__ __forceinline__ ush f2bf(float x) {
    unsigned u = __builtin_bit_cast(unsigned, x);
    u += 0x7FFFu + ((u >> 16) & 1u);
    return (ush)(u >> 16);
}
__device__ __forceinline__ float bf2f(ush h) {
    unsigned u = ((unsigned)h) << 16;
    return __builtin_bit_cast(float, u);
}
__device__ __forceinline__ void splitf(float x, ush& hi, ush& lo) {
    hi = f2bf(x);
    lo = f2bf(x - bf2f(hi));
}

__device__ __forceinline__ void gl_lds16(const ush* g, short* l) {
    __builtin_amdgcn_global_load_lds(
        (const __attribute__((address_space(1))) unsigned*)(const void*)g,
        (__attribute__((address_space(3))) unsigned*)l, 16, 0, 0);
}

// per-level work descriptors (kernel args by value)
struct Lvl3 {
    const ush* xh; const ush* xl;    // input planes (padded NHWC hi/lo)
    ush* yh; ush* yl;                // output planes
    const float* bias;
    int wofs, logS, logHW, bstart;   // weight elem offset; block range start
};
struct Tab3 { Lvl3 l[4]; };

struct LvlS {
    const ush* xh; const ush* xl;    // input planes (unpadded NHWC hi/lo)
    int abase, logHW, bstart, ibase;
};
struct TabS { LvlS l[4]; };

// ---------------------------------------------------------------------------
// conv3g: deep 3x3 conv, fused multi-level. K=2304, Cout=256, 256 px/block.
// 8 waves: wm=w&1 (co half, 128 rows), wn=w>>1 (px quarter, 64 cols).
// LDS buffer (64KB): Ah[256][32] | Al | Bh[256][32] | Bl (8192 shorts each).
// Staging: role=w>>1 (0:Ah 1:Al 2:Bh 3:Bl), part=w&1 (128-row half); every
// wave 8 x gl_lds16 per chunk. Slot swizzle (both sides, proven 0-conflict):
// seg(row,slot) = slot ^ ((row>>1)&3).
// OM: 0 = padded NHWC hi/lo out; 1 = unpadded NHWC hi/lo out.  BNR: BN+ReLU.
// ---------------------------------------------------------------------------
#define MFMA3(AH, AL, BH, BL, ACC)                                            \
    ACC = __builtin_amdgcn_mfma_f32_16x16x32_bf16(AH, BH, ACC, 0, 0, 0);      \
    ACC = __builtin_amdgcn_mfma_f32_16x16x32_bf16(AH, BL, ACC, 0, 0, 0);      \
    ACC = __builtin_amdgcn_mfma_f32_16x16x32_bf16(AL, BH, ACC, 0, 0, 0);

// operand reads (static indices; A row-block i -> offset i*512 from abA)
#define RDA0(BP)                                                              \
    _Pragma("unroll")                                                         \
    for (int i = 0; i < 4; ++i) {                                             \
        a0h[i] = *(const v8s*)((BP) + abA + i * 512);                         \
        a0l[i] = *(const v8s*)((BP) + abA + 8192 + i * 512);                  \
    }
#define RDA1(BP)                                                              \
    _Pragma("unroll")                                                         \
    for (int i = 0; i < 4; ++i) {                                             \
        a1h[i] = *(const v8s*)((BP) + abA + (4 + i) * 512);                   \
        a1l[i] = *(const v8s*)((BP) + abA + 8192 + (4 + i) * 512);            \
    }
#define RDB01(BP)                                                             \
    _Pragma("unroll")                                                         \
    for (int j = 0; j < 2; ++j) {                                             \
        b0h[j] = *(const v8s*)((BP) + abB + j * 512);                         \
        b0l[j] = *(const v8s*)((BP) + abB + 8192 + j * 512);                  \
    }
#define RDB23(BP)                                                             \
    _Pragma("unroll")                                                         \
    for (int j = 0; j < 2; ++j) {                                             \
        b1h[j] = *(const v8s*)((BP) + abB + (2 + j) * 512);                   \
        b1l[j] = *(const v8s*)((BP) + abB + 8192 + (2 + j) * 512);            \
    }

// 24 MFMAs: A regs (AH,AL) x B regs (BH,BL) -> acc[IB..IB+3][JB..JB+1]
#define MF24(AH, AL, BH, BL, IB, JB)                                          \
    __builtin_amdgcn_s_setprio(1);                                            \
    _Pragma("unroll")                                                         \
    for (int j = 0; j < 2; ++j) {                                             \
        _Pragma("unroll")                                                     \
        for (int i = 0; i < 4; ++i) {                                         \
            MFMA3(AH[i], AL[i], BH[j], BL[j], acc[(IB)+i][(JB)+j]);           \
        }                                                                     \
    }                                                                         \
    __builtin_amdgcn_s_setprio(0);

template <int OM, bool BNR>
__global__ __launch_bounds__(512, 2)
void conv3g(Tab3 T,
            const ush* __restrict__ Wh, const ush* __restrict__ Wl,
            const float* __restrict__ bng, const float* __restrict__ bnb,
            const float* __restrict__ bnm, const float* __restrict__ bnv)
{
    constexpr int K = 2304, KC = 72;
    constexpr int BUFS = 32768;   // shorts per buffer (64KB)

    // bijective XCD-aware swizzle on the 1-D grid
    const int nwg = gridDim.x;
    const int flat = blockIdx.x;
    const int xcd = flat & 7, sidx = flat >> 3;
    const int q = nwg >> 3, r8 = nwg & 7;
    const int nf = (xcd < r8 ? xcd * (q + 1) : r8 * (q + 1) + (xcd - r8) * q) + sidx;

    // level lookup
    int li = 0;
    if (nf >= T.l[1].bstart) li = 1;
    if (nf >= T.l[2].bstart) li = 2;
    if (nf >= T.l[3].bstart) li = 3;
    const int logS = T.l[li].logS, logHW = T.l[li].logHW;
    const int S = 1 << logS, HW = 1 << logHW, P = S + 2;
    const ush* __restrict__ Xh = T.l[li].xh;
    const ush* __restrict__ Xl = T.l[li].xl;
    ush* __restrict__ Yh = T.l[li].yh;
    ush* __restrict__ Yl = T.l[li].yl;
    const float* __restrict__ bias = T.l[li].bias;
    const int wofs = T.l[li].wofs;
    const int n0 = (nf - T.l[li].bstart) * 256;

    __shared__ __align__(16) short lds[2][BUFS];
    // buffer layout (shorts): Ah 0 | Al 8192 | Bh 16384 | Bl 24576

    const int tid = threadIdx.x;
    const int lane = tid & 63, w = tid >> 6;
    const int wm = w & 1, wn = w >> 1;       // wave tile: 128 co x 64 px
    const int l15 = lane & 15, l4 = lane >> 4;
    const int lr = lane >> 2, ls = lane & 3;
    const int sw = ls ^ ((lr >> 1) & 3);

    const int role = w >> 1, part = w & 1;   // 0:Ah 1:Al 2:Bh 3:Bl
    const ush* gsrc = role == 0 ? Wh + wofs : role == 1 ? Wl + wofs
                    : role == 2 ? Xh : Xl;
    const int poff = role * 8192 + part * 4096;

    int sb[8];
    if (role < 2) {
#pragma unroll
        for (int t = 0; t < 8; ++t)
            sb[t] = (part * 128 + t * 16 + lr) * K + sw * 8;
    } else {
#pragma unroll
        for (int t = 0; t < 8; ++t) {
            const int p = n0 + part * 128 + t * 16 + lr;
            const int bb = p >> logHW, hw = p & (HW - 1);
            const int oh = hw >> logS, ow = hw & (S - 1);
            sb[t] = ((bb * P + oh + 1) * P + ow + 1) * 256 + sw * 8;
        }
    }

    // stage all 8 loads of chunk c into buffer u
    auto stage_g = [&](int u, int c) {
        short* db = &lds[0][0] + u * BUFS + poff;
        int coff;
        if (role < 2) coff = c * 32;
        else {
            const int rs = c >> 3;             // tap 0..8 (uniform)
            const int rr = (rs * 11) >> 5;     // rs / 3
            const int ss = rs - 3 * rr;
            coff = ((rr - 1) * P + (ss - 1)) * 256 + (c & 7) * 32;
        }
#pragma unroll
        for (int t = 0; t < 8; ++t)
            gl_lds16(gsrc + (sb[t] + coff), db + t * 512);
    };

    // fragment base offsets within a buffer (shorts); per-i/j step = 512
    const int slr = (l4 ^ ((l15 >> 1) & 3)) * 8;
    const int abA = (wm * 128 + l15) * 32 + slr;
    const int abB = 16384 + (wn * 64 + l15) * 32 + slr;

    v4f acc[8][4] = {};
    v8s a0h[4], a0l[4];       // A-half0 of current chunk (prefetched)
    v8s a1h[4], a1l[4];       // A-half1 (read in ph1)
    v8s b0h[2], b0l[2];       // B cols 0,1 (prefetched)
    v8s b1h[2], b1l[2];       // B cols 2,3 (read in ph1)

    // prologue: chunks 0,1 staged; counted drain to "chunk 0 arrived";
    // preload chunk 0's A-half0 + B01 (ph1's LGK(0) covers them).
    stage_g(0, 0);
    stage_g(1, 1);
    VMW(8); SB0();
    __builtin_amdgcn_s_barrier();
    SB0();
    {
        const short* bp = &lds[0][0];
        RDA0(bp); RDB01(bp);
    }

    int cur = 0;
    for (int c = 0; c < KC; ++c) {
        const short* bp  = &lds[0][0] + cur * BUFS;          // chunk c
        const short* bpn = &lds[0][0] + (cur ^ 1) * BUFS;    // chunk c+1
        const bool p1 = (c + 1) < KC;
        const bool p2 = (c + 2) < KC;

        // ph1: prefetched a0/b01 ready; issue b23 then a1; MFMA rows0-3 x c0-1
        LGK(0); SB0();
        RDB23(bp); RDA1(bp);
        MF24(a0h, a0l, b0h, b0l, 0, 0);

        // ph2: b23 landed (a1 may still fly); MFMA rows0-3 x c2-3
        LGK(8); SB0();
        MF24(a0h, a0l, b1h, b1l, 0, 2);

        // mid-sync: my buf[cur] reads all done + my DMA(c+1) drained
        LGK(0); SB0();
        VMW(0); SB0();
        __builtin_amdgcn_s_barrier();
        SB0();

        // ph3: prefetch A-half0(c+1) into dead a0; stage DMA(c+2)->buf[cur];
        //      MFMA rows4-7 x c2-3
        if (p1) { RDA0(bpn); }
        if (p2) stage_g(cur, c + 2);
        MF24(a1h, a1l, b1h, b1l, 4, 2);

        // ph4: MFMA rows4-7 x c0-1; then prefetch B01(c+1) (anti-dep safe)
        MF24(a1h, a1l, b0h, b0l, 4, 0);
        if (p1) { RDB01(bpn); }

        cur ^= 1;
    }

    // ---- epilogue: col = lane&15 (pixel), row = (lane>>4)*4+e (co) ----
#pragma unroll
    for (int i = 0; i < 8; ++i) {
        const int co = wm * 128 + i * 16 + l4 * 4;
        float sc[4], sh[4];
#pragma unroll
        for (int e = 0; e < 4; ++e) {
            if (BNR) {
                const float inv = bng[co + e] * rsqrtf(bnv[co + e] + 1e-5f);
                sc[e] = inv;
                sh[e] = (bias[co + e] - bnm[co + e]) * inv + bnb[co + e];
            } else { sc[e] = 1.f; sh[e] = bias[co + e]; }
        }
#pragma unroll
        for (int j = 0; j < 4; ++j) {
            const int ncol = n0 + wn * 64 + j * 16 + l15;
            const int b  = ncol >> logHW;
            const int hw = ncol & (HW - 1);
            float val[4];
#pragma unroll
            for (int e = 0; e < 4; ++e) {
                float x = acc[i][j][e] * sc[e] + sh[e];
                if (BNR) x = fmaxf(x, 0.f);
                val[e] = x;
            }
            int pidx;
            if (OM == 0) {
                const int oh = hw >> logS, ow = hw & (S - 1);
                pidx = (b * P + oh + 1) * P + ow + 1;
            } else {
                pidx = ncol;
            }
            const int addr = pidx * 256 + co;
            ush hs[4], ls2[4];
#pragma unroll
            for (int e = 0; e < 4; ++e) splitf(val[e], hs[e], ls2[e]);
            *(uint2*)&Yh[addr] = make_uint2(hs[0] | ((unsigned)hs[1] << 16),
                                            hs[2] | ((unsigned)hs[3] << 16));
            *(uint2*)&Yl[addr] = make_uint2(ls2[0] | ((unsigned)ls2[1] << 16),
                                            ls2[2] | ((unsigned)ls2[3] << 16));
        }
    }
}

// ---------------------------------------------------------------------------
// Fused scatter head-conv2 (1x1, K=256, Cout=9*DD, fp32 scatter epilogue).
// 4 waves, 128 px/block, co0 = 0 (Cout <= 128; weights zero-padded to 128).
// ---------------------------------------------------------------------------
template <int DD>
__global__ __launch_bounds__(256, 3)
void conv_sf(TabS T, const ush* __restrict__ Wh, const ush* __restrict__ Wl,
             const float* __restrict__ bias, float* __restrict__ out)
{
    constexpr int K = 256, KC = 8, Cout = 9 * DD;
    constexpr int coloff = (DD == 10) ? 4 : 0;

    const int nwg = gridDim.x;
    const int flat = blockIdx.x;
    const int xcd = flat & 7, sidx = flat >> 3;
    const int q = nwg >> 3, r8 = nwg & 7;
    const int nf = (xcd < r8 ? xcd * (q + 1) : r8 * (q + 1) + (xcd - r8) * q) + sidx;

    int li = 0;
    if (nf >= T.l[1].bstart) li = 1;
    if (nf >= T.l[2].bstart) li = 2;
    if (nf >= T.l[3].bstart) li = 3;
    const int logHW = T.l[li].logHW;
    const int HW = 1 << logHW;
    const ush* __restrict__ Xh = T.l[li].xh;
    const ush* __restrict__ Xl = T.l[li].xl;
    const int abase = T.l[li].abase, ibase = T.l[li].ibase;
    const int n0 = (nf - T.l[li].bstart) * 128;

    __shared__ short lds[4][128][32];

    const int tid = threadIdx.x;
    const int lane = tid & 63;
    const int w = tid >> 6;
    const int wm = w & 1, wn = w >> 1;
    const int l15 = lane & 15, l4 = lane >> 4;
    const int lr = lane >> 2, ls = lane & 3;
    const int sw = ls ^ ((lr >> 1) & 3);
    const ush* gsrc = (w == 0) ? Wh : (w == 1) ? Wl : (w == 2) ? Xh : Xl;
    int sb[8];
    if (w < 2) {
#pragma unroll
        for (int t = 0; t < 8; ++t)
            sb[t] = (t * 16 + lr) * K + sw * 8;
    } else {
#pragma unroll
        for (int t = 0; t < 8; ++t)
            sb[t] = (n0 + t * 16 + lr) * 256 + sw * 8;
    }
    short* mypl = &lds[w][0][0];
    const int slA = (l4 ^ ((l15 >> 1) & 3)) * 8;

    v4f acc[4][4] = {};

    for (int c = 0; c < KC; ++c) {
        const int coff = c * 32;
#pragma unroll
        for (int t = 0; t < 8; ++t)
            gl_lds16(gsrc + (sb[t] + coff), mypl + t * 512);

        __syncthreads();

        v8s ah[4], al[4];
#pragma unroll
        for (int i = 0; i < 4; ++i) {
            ah[i] = *(const v8s*)&lds[0][wm * 64 + i * 16 + l15][slA];
            al[i] = *(const v8s*)&lds[1][wm * 64 + i * 16 + l15][slA];
        }
#pragma unroll
        for (int j = 0; j < 4; ++j) {
            const v8s bh = *(const v8s*)&lds[2][wn * 64 + j * 16 + l15][slA];
            const v8s bl = *(const v8s*)&lds[3][wn * 64 + j * 16 + l15][slA];
#pragma unroll
            for (int i = 0; i < 4; ++i) {
                acc[i][j] = __builtin_amdgcn_mfma_f32_16x16x32_bf16(ah[i], bh, acc[i][j], 0, 0, 0);
                acc[i][j] = __builtin_amdgcn_mfma_f32_16x16x32_bf16(ah[i], bl, acc[i][j], 0, 0, 0);
                acc[i][j] = __builtin_amdgcn_mfma_f32_16x16x32_bf16(al[i], bh, acc[i][j], 0, 0, 0);
            }
        }
        __syncthreads();
    }

#pragma unroll
    for (int i = 0; i < 4; ++i) {
        const int co = wm * 64 + i * 16 + l4 * 4;
        float sh[4];
#pragma unroll
        for (int e = 0; e < 4; ++e)
            sh[e] = (co + e < Cout) ? bias[co + e] : 0.f;
#pragma unroll
        for (int j = 0; j < 4; ++j) {
            const int ncol = n0 + wn * 64 + j * 16 + l15;
            const int b  = ncol >> logHW;
            const int hw = ncol & (HW - 1);
#pragma unroll
            for (int e = 0; e < 4; ++e) {
                const int c2 = co + e;
                if (c2 < Cout) {
                    const float val = acc[i][j][e] + sh[e];
                    const int a = c2 / DD, cl = c2 - a * DD;
                    out[(size_t)((b + ibase) * TOTAL_ANCH + abase + hw * 9 + a) * 14
                        + coloff + cl] = val;
                }
            }
        }
    }
}

// ---------------------------------------------------------------------------
// R1 128^2 kernel — retained for the 1x1 lateral convs (KS=1, OM=0).
// ---------------------------------------------------------------------------
template <int KS, int OM, bool BNR, int DD>
__global__ __launch_bounds__(256, 3)
void conv_mfma(const ush* __restrict__ Xh, const ush* __restrict__ Xl,
               const ush* __restrict__ Wh, const ush* __restrict__ Wl,
               const float* __restrict__ bias,
               ush* __restrict__ Yh, ush* __restrict__ Yl,
               int K, int logS, int logHW, int Kin)
{
    const int tid = threadIdx.x;

    const int nwg  = gridDim.x * gridDim.y;
    const int flat = blockIdx.y * gridDim.x + blockIdx.x;
    const int xcd = flat & 7, sidx = flat >> 3;
    const int q = nwg >> 3, r8 = nwg & 7;
    const int nf = (xcd < r8 ? xcd * (q + 1) : r8 * (q + 1) + (xcd - r8) * q) + sidx;
    int bx, by;
    if (gridDim.y == 2) { bx = nf >> 1; by = nf & 1; }
    else                { bx = nf;      by = 0;      }

    const int n0  = bx * 128;
    const int co0 = by * 128;
    const int S = 1 << logS, HW = 1 << logHW, P = S + 2;

    __shared__ short lds[4][128][32];

    const int lane = tid & 63;
    const int w = tid >> 6;
    const int wm = w & 1, wn = w >> 1;
    const int l15 = lane & 15, l4 = lane >> 4;

    const int lr = lane >> 2, ls = lane & 3;
    const int sw = ls ^ ((lr >> 1) & 3);
    const ush* gsrc = (w == 0) ? Wh : (w == 1) ? Wl : (w == 2) ? Xh : Xl;
    int sb[8];
    if (w < 2) {
#pragma unroll
        for (int t = 0; t < 8; ++t)
            sb[t] = (co0 + t * 16 + lr) * K + sw * 8;
    } else {
#pragma unroll
        for (int t = 0; t < 8; ++t) {
            const int p = n0 + t * 16 + lr;
            sb[t] = p * Kin + sw * 8;
        }
    }
    short* mypl = &lds[w][0][0];

    const int KC = K >> 5;
    const int slA = (l4 ^ ((l15 >> 1) & 3)) * 8;

    v4f acc[4][4] = {};

    for (int c = 0; c < KC; ++c) {
        const int coff = c * 32;
#pragma unroll
        for (int t = 0; t < 8; ++t)
            gl_lds16(gsrc + (sb[t] + coff), mypl + t * 512);

        __syncthreads();

        v8s ah[4], al[4];
#pragma unroll
        for (int i = 0; i < 4; ++i) {
            ah[i] = *(const v8s*)&lds[0][wm * 64 + i * 16 + l15][slA];
            al[i] = *(const v8s*)&lds[1][wm * 64 + i * 16 + l15][slA];
        }
#pragma unroll
        for (int j = 0; j < 4; ++j) {
            const v8s bh = *(const v8s*)&lds[2][wn * 64 + j * 16 + l15][slA];
            const v8s bl = *(const v8s*)&lds[3][wn * 64 + j * 16 + l15][slA];
#pragma unroll
            for (int i = 0; i < 4; ++i) {
                acc[i][j] = __builtin_amdgcn_mfma_f32_16x16x32_bf16(ah[i], bh, acc[i][j], 0, 0, 0);
                acc[i][j] = __builtin_amdgcn_mfma_f32_16x16x32_bf16(ah[i], bl, acc[i][j], 0, 0, 0);
                acc[i][j] = __builtin_amdgcn_mfma_f32_16x16x32_bf16(al[i], bh, acc[i][j], 0, 0, 0);
            }
        }
        __syncthreads();
    }

#pragma unroll
    for (int i = 0; i < 4; ++i) {
        const int cob = wm * 64 + i * 16 + l4 * 4;
        const int co  = co0 + cob;
        float sh[4];
#pragma unroll
        for (int e = 0; e < 4; ++e) sh[e] = bias[co + e];
#pragma unroll
        for (int j = 0; j < 4; ++j) {
            const int ncol = n0 + wn * 64 + j * 16 + l15;
            const int b  = ncol >> logHW;
            const int hw = ncol & (HW - 1);
            float val[4];
#pragma unroll
            for (int e = 0; e < 4; ++e) val[e] = acc[i][j][e] + sh[e];
            int pidx;
            if (OM == 0) {
                const int oh = hw >> logS, ow = hw & (S - 1);
                pidx = (b * P + oh + 1) * P + ow + 1;
            } else {
                pidx = ncol;
            }
            const int addr = pidx * 256 + co;
            ush hs[4], ls2[4];
#pragma unroll
            for (int e = 0; e < 4; ++e) splitf(val[e], hs[e], ls2[e]);
            *(uint2*)&Yh[addr] = make_uint2(hs[0] | ((unsigned)hs[1] << 16),
                                            hs[2] | ((unsigned)hs[3] << 16));
            *(uint2*)&Yl[addr] = make_uint2(ls2[0] | ((unsigned)ls2[1] << 16),
                                            ls2[2] | ((unsigned)ls2[3] << 16));
        }
    }
}

// ---- prep / glue kernels -------------------------------------------------

__global__ void w3_prep(const float* __restrict__ W, ush* __restrict__ wh,
                        ush* __restrict__ wl, int total) {
    const int idx = blockIdx.x * 256 + threadIdx.x;
    if (idx >= total) return;
    const int co5 = idx / 2304;
    const int kk  = idx - co5 * 2304;
    const int rs = kk >> 8, ci = kk & 255;
    splitf(W[(co5 * 256 + ci) * 9 + rs], wh[idx], wl[idx]);
}

__global__ void w1_prep(const float* __restrict__ W, ush* __restrict__ wh,
                        ush* __restrict__ wl, int Cin, int Kp, int Cout, int total) {
    const int idx = blockIdx.x * 256 + threadIdx.x;
    if (idx >= total) return;
    const int co = idx / Kp;
    const int k  = idx - co * Kp;
    const float x = (co < Cout && k < Cin) ? W[co * Cin + k] : 0.f;
    splitf(x, wh[idx], wl[idx]);
}

__global__ void in_prep(const float* __restrict__ f, ush* __restrict__ xh,
                        ush* __restrict__ xl, int Cin, int Kp, int logHW, int total) {
    const int idx = blockIdx.x * 256 + threadIdx.x;
    if (idx >= total) return;
    const int c = idx % Kp;
    const int n = idx / Kp;
    const int b  = n >> logHW;
    const int hw = n & ((1 << logHW) - 1);
    const float x = (c < Cin) ? f[((b * Cin + c) << logHW) + hw] : 0.f;
    splitf(x, xh[idx], xl[idx]);
}

__global__ void upsample_hl(ush* __restrict__ fh, ush* __restrict__ fl,
                            const ush* __restrict__ ch, const ush* __restrict__ cl2,
                            int logSf, int total) {
    const int idx = blockIdx.x * 256 + threadIdx.x;
    if (idx >= total) return;
    const int ci = idx & 255;
    const int r  = idx >> 8;
    const int Sf = 1 << logSf;
    const int wf = r & (Sf - 1);
    const int hf = (r >> logSf) & (Sf - 1);
    const int b  = r >> (2 * logSf);
    const int Pf = Sf + 2, Pc = (Sf >> 1) + 2;
    const int fi = ((b * Pf + hf + 1) * Pf + wf + 1) * 256 + ci;
    const int cx = ((b * Pc + (hf >> 1) + 1) * Pc + (wf >> 1) + 1) * 256 + ci;
    const float x = bf2f(fh[fi]) + bf2f(fl[fi]) + bf2f(ch[cx]) + bf2f(cl2[cx]);
    splitf(x, fh[fi], fl[fi]);
}

__global__ void ring_zero(ush* __restrict__ yh, ush* __restrict__ yl, int S, int total) {
    const int idx = blockIdx.x * 256 + threadIdx.x;
    if (idx >= total) return;
    const int ci = idx & 255;
    const int r  = idx >> 8;
    const int P = S + 2;
    const int ring = 4 * P - 4;
    const int pr = r % ring;
    const int b  = r / ring;
    int ph, pw;
    if (pr < P)            { ph = 0;     pw = pr; }
    else if (pr < 2 * P)   { ph = P - 1; pw = pr - P; }
    else { const int q = pr - 2 * P; ph = 1 + (q >> 1); pw = (q & 1) ? (P - 1) : 0; }
    const int a = ((b * P + ph) * P + pw) * 256 + ci;
    yh[a] = 0; yl[a] = 0;
}

// ---------------------------------------------------------------------------

extern "C" void kernel_launch(void* const* d_in, const int* in_sizes, int n_in,
                              void* d_out, int out_size, void* d_ws, size_t ws_size,
                              hipStream_t stream)
{
    const float* f[5];     const float* lat_w[5];
    for (int i = 0; i < 5; ++i) f[i] = (const float*)d_in[i];
    for (int i = 0; i < 5; ++i) lat_w[i] = (const float*)d_in[5 + i];
    const float* lat_b  = (const float*)d_in[10];
    const float* fpn_w  = (const float*)d_in[11];
    const float* fpn_b  = (const float*)d_in[12];
    const float* cls_w1 = (const float*)d_in[13];
    const float* cls_b1 = (const float*)d_in[14];
    const float* cls_g  = (const float*)d_in[15];
    const float* cls_bt = (const float*)d_in[16];
    const float* cls_m  = (const float*)d_in[17];
    const float* cls_v  = (const float*)d_in[18];
    const float* cls_w2 = (const float*)d_in[19];
    const float* cls_b2 = (const float*)d_in[20];
    const float* reg_w1 = (const float*)d_in[21];
    const float* reg_b1 = (const float*)d_in[22];
    const float* reg_g  = (const float*)d_in[23];
    const float* reg_bt = (const float*)d_in[24];
    const float* reg_m  = (const float*)d_in[25];
    const float* reg_v  = (const float*)d_in[26];
    const float* reg_w2 = (const float*)d_in[27];
    const float* reg_b2 = (const float*)d_in[28];

    float* out = (float*)d_out;
    ush*   ws16 = (ush*)d_ws;

    static const int S_[5]     = {128, 64, 32, 16, 8};
    static const int logS_[5]  = {7, 6, 5, 4, 3};
    static const int logHW_[5] = {14, 12, 10, 8, 6};
    static const int HW_[5]    = {16384, 4096, 1024, 256, 64};
    static const int Cin_[5]   = {32, 48, 96, 136, 232};
    static const int Kp_[5]    = {32, 64, 96, 160, 256};
    static const int abase_[5] = {0, 147456, 184320, 193536, 195840};
    constexpr int BIG = 0x7fffffff;

    size_t off = 0;
    auto alloc = [&](size_t elems) {
        ush* p = ws16 + off;
        off += (elems + 63) & ~(size_t)63;
        return p;
    };

    // --- persistent: padded lateral planes (reused as head-conv1 tmp) ---
    ush *lat_h[5], *lat_l[5];
    for (int i = 0; i < 5; ++i) {
        const int P = S_[i] + 2;
        const size_t e = (size_t)2048 * P * P;   // 8 images * P*P * 256
        lat_h[i] = alloc(e); lat_l[i] = alloc(e);
    }
    const size_t lat_bytes = off * sizeof(ush);

    // --- shared transient arena (69.2 MB) ---
    const size_t ARENA_E = (size_t)2 * 4 * 130 * 130 * 256;
    ush* arena = alloc(ARENA_E);

    // --- weights (head conv2 padded to 128 co-rows for unguarded DMA) ---
    ush* fw_h = alloc((size_t)5 * 256 * 2304); ush* fw_l = alloc((size_t)5 * 256 * 2304);
    ush* cw_h = alloc(256 * 2304);             ush* cw_l = alloc(256 * 2304);
    ush* rw_h = alloc(256 * 2304);             ush* rw_l = alloc(256 * 2304);
    ush *lw_h[5], *lw_l[5];
    for (int i = 0; i < 5; ++i) { lw_h[i] = alloc(256 * Kp_[i]); lw_l[i] = alloc(256 * Kp_[i]); }
    ush* c2_h = alloc(128 * 256); ush* c2_l = alloc(128 * 256);
    ush* r2_h = alloc(128 * 256); ush* r2_l = alloc(128 * 256);

    hipMemsetAsync(ws16, 0, lat_bytes, stream);

    // --- weight prep ---
    {
        int t = 5 * 256 * 2304;
        w3_prep<<<dim3((t + 255) / 256), 256, 0, stream>>>(fpn_w, fw_h, fw_l, t);
        t = 256 * 2304;
        w3_prep<<<dim3((t + 255) / 256), 256, 0, stream>>>(cls_w1, cw_h, cw_l, t);
        w3_prep<<<dim3((t + 255) / 256), 256, 0, stream>>>(reg_w1, rw_h, rw_l, t);
        for (int i = 0; i < 5; ++i) {
            t = 256 * Kp_[i];
            w1_prep<<<dim3((t + 255) / 256), 256, 0, stream>>>(lat_w[i], lw_h[i], lw_l[i], Cin_[i], Kp_[i], 256, t);
        }
        t = 128 * 256;
        w1_prep<<<dim3((t + 255) / 256), 256, 0, stream>>>(cls_w2, c2_h, c2_l, 256, 256, 90, t);
        w1_prep<<<dim3((t + 255) / 256), 256, 0, stream>>>(reg_w2, r2_h, r2_l, 256, 256, 36, t);
    }

    // --- input conversion + lateral 1x1 convs (arena transient) ---
    for (int i = 0; i < 5; ++i) {
        const int N = 8 * HW_[i];
        const int t = N * Kp_[i];
        ush* xh = arena;
        ush* xl = arena + (size_t)N * Kp_[i];
        in_prep<<<dim3((t + 255) / 256), 256, 0, stream>>>(f[i], xh, xl, Cin_[i], Kp_[i], logHW_[i], t);
        conv_mfma<1, 0, false, 0><<<dim3(N / 128, 2), 256, 0, stream>>>(
            xh, xl, lw_h[i], lw_l[i], lat_b + i * 256,
            lat_h[i], lat_l[i],
            Kp_[i], logS_[i], logHW_[i], Kp_[i]);
    }

    // --- top-down pathway ---
    for (int i = 4; i >= 1; --i) {
        const int t = 8 * HW_[i - 1] * 256;
        upsample_hl<<<dim3((t + 255) / 256), 256, 0, stream>>>(
            lat_h[i - 1], lat_l[i - 1], lat_h[i], lat_l[i], logS_[i - 1], t);
    }

    // --- levels 1..4 FUSED: all 4 fpn plane pairs resident in arena ---
    ush *fpn_h4[5], *fpn_l4[5];
    {
        size_t o = 0;
        for (int i = 1; i < 5; ++i) {
            const int P = S_[i] + 2;
            fpn_h4[i] = arena + o; o += (size_t)2048 * P * P;
            fpn_l4[i] = arena + o; o += (size_t)2048 * P * P;
        }
    }
    for (int i = 1; i < 5; ++i) {
        const int P = S_[i] + 2;
        const int rt = 8 * (4 * P - 4) * 256;
        ring_zero<<<dim3((rt + 255) / 256), 256, 0, stream>>>(fpn_h4[i], fpn_l4[i], S_[i], rt);
    }
    static const int bstart4[4] = {0, 128, 160, 168};   // 128+32+8+2 = 170 (256px blocks)
    static const int bstartS[4] = {0, 256, 320, 336};   // 340 (128px blocks, conv_sf)

    {   // fused fpn conv (per-level weight slice + bias)
        Tab3 T{};
        for (int k = 0; k < 4; ++k) {
            const int i = k + 1;
            T.l[k] = Lvl3{ lat_h[i], lat_l[i], fpn_h4[i], fpn_l4[i],
                           fpn_b + i * 256, i * 256 * 2304,
                           logS_[i], logHW_[i], bstart4[k] };
        }
        conv3g<0, false><<<dim3(170), 512, 0, stream>>>(
            T, fw_h, fw_l, nullptr, nullptr, nullptr, nullptr);
    }
    {   // fused cls conv1 -> tmp (lat planes)
        Tab3 T{};
        for (int k = 0; k < 4; ++k) {
            const int i = k + 1;
            T.l[k] = Lvl3{ fpn_h4[i], fpn_l4[i], lat_h[i], lat_l[i],
                           cls_b1, 0, logS_[i], logHW_[i], bstart4[k] };
        }
        conv3g<1, true><<<dim3(170), 512, 0, stream>>>(
            T, cw_h, cw_l, cls_g, cls_bt, cls_m, cls_v);
    }
    {   // fused cls conv2 scatter
        TabS T{};
        for (int k = 0; k < 4; ++k) {
            const int i = k + 1;
            T.l[k] = LvlS{ lat_h[i], lat_l[i], abase_[i], logHW_[i], bstartS[k], 0 };
        }
        conv_sf<10><<<dim3(340), 256, 0, stream>>>(T, c2_h, c2_l, cls_b2, out);
    }
    {   // fused reg conv1 -> tmp
        Tab3 T{};
        for (int k = 0; k < 4; ++k) {
            const int i = k + 1;
            T.l[k] = Lvl3{ fpn_h4[i], fpn_l4[i], lat_h[i], lat_l[i],
                           reg_b1, 0, logS_[i], logHW_[i], bstart4[k] };
        }
        conv3g<1, true><<<dim3(170), 512, 0, stream>>>(
            T, rw_h, rw_l, reg_g, reg_bt, reg_m, reg_v);
    }
    {   // fused reg conv2 scatter
        TabS T{};
        for (int k = 0; k < 4; ++k) {
            const int i = k + 1;
            T.l[k] = LvlS{ lat_h[i], lat_l[i], abase_[i], logHW_[i], bstartS[k], 0 };
        }
        conv_sf<4><<<dim3(340), 256, 0, stream>>>(T, r2_h, r2_l, reg_b2, out);
    }

    // --- level 0: two 4-image groups (1-entry tables; 256 blocks = 1 round) ---
    {
        const int P = 130;
        const size_t padg = (size_t)4 * P * P * 256;     // padded, 4 images
        const size_t unpg = (size_t)4 * 16384 * 256;     // unpadded, 4 images
        for (int g = 0; g < 2; ++g) {
            ush* fpn_h = arena;
            ush* fpn_l = arena + padg;
            ush* lat0p_h = lat_h[0] + (size_t)g * padg;
            ush* lat0p_l = lat_l[0] + (size_t)g * padg;
            ush* tmp_h   = lat_h[0] + (size_t)g * unpg;
            ush* tmp_l   = lat_l[0] + (size_t)g * unpg;
            const int rt = 4 * (4 * P - 4) * 256;
            ring_zero<<<dim3((rt + 255) / 256), 256, 0, stream>>>(fpn_h, fpn_l, 128, rt);

            Tab3 T{};
            T.l[0] = Lvl3{ lat0p_h, lat0p_l, fpn_h, fpn_l, fpn_b, 0, 7, 14, 0 };
            for (int k = 1; k < 4; ++k) T.l[k].bstart = BIG;
            conv3g<0, false><<<dim3(256), 512, 0, stream>>>(
                T, fw_h, fw_l, nullptr, nullptr, nullptr, nullptr);

            Tab3 Tc{};
            Tc.l[0] = Lvl3{ fpn_h, fpn_l, tmp_h, tmp_l, cls_b1, 0, 7, 14, 0 };
            for (int k = 1; k < 4; ++k) Tc.l[k].bstart = BIG;
            conv3g<1, true><<<dim3(256), 512, 0, stream>>>(
                Tc, cw_h, cw_l, cls_g, cls_bt, cls_m, cls_v);

            TabS Ts{};
            Ts.l[0] = LvlS{ tmp_h, tmp_l, 0, 14, 0, 4 * g };
            for (int k = 1; k < 4; ++k) Ts.l[k].bstart = BIG;
            conv_sf<10><<<dim3(512), 256, 0, stream>>>(Ts, c2_h, c2_l, cls_b2, out);

            Tab3 Tr{};
            Tr.l[0] = Lvl3{ fpn_h, fpn_l, tmp_h, tmp_l, reg_b1, 0, 7, 14, 0 };
            for (int k = 1; k < 4; ++k) Tr.l[k].bstart = BIG;
            conv3g<1, true><<<dim3(256), 512, 0, stream>>>(
                Tr, rw_h, rw_l, reg_g, reg_bt, reg_m, reg_v);

            TabS Tq{};
            Tq.l[0] = LvlS{ tmp_h, tmp_l, 0, 14, 0, 4 * g };
            for (int k = 1; k < 4; ++k) Tq.l[k].bstart = BIG;
            conv_sf<4><<<dim3(512), 256, 0, stream>>>(Tq, r2_h, r2_l, reg_b2, out);
        }
    }
}